// Round 5
// baseline (496.252 us; speedup 1.0000x reference)
//
#include <hip/hip_runtime.h>

// Problem constants (AttentionalCopula)
constexpr int kB = 16, kD = 256, kNH = 512, kNV = 256, kW = 768;
constexpr int kL = 4, kH = 8, kA = 64, kHA = 512, kM = 512, kR = 128;
constexpr int kKP = 288;  // K=257 zero-padded to multiple of 32
constexpr int kRows = kB * kNV;  // 4096

typedef __bf16 bf16x8 __attribute__((ext_vector_type(8)));
typedef __bf16 bf16x4 __attribute__((ext_vector_type(4)));
typedef float f32x4 __attribute__((ext_vector_type(4)));

__device__ inline void load_lds16(const __bf16* g, __bf16* l) {
  __builtin_amdgcn_global_load_lds(
      (const __attribute__((address_space(1))) void*)g,
      (__attribute__((address_space(3))) void*)l, 16, 0, 0);
}

// ---------------- merged prep kernel (1 launch) ----------------
constexpr int kP1 = kB * kW * kKP;        // ki
constexpr int kP2 = 4096 * kKP;           // kv weights
constexpr int kP3 = 12 * 512 * 512;       // ff weights
constexpr int kP4 = 200704;               // ds_wt, de_wt, kvb
constexpr int kP5 = 16;                   // zero d_out
constexpr int kPT = kP1 + kP2 + kP3 + kP4 + kP5;

__global__ void prep_kernel(const float* __restrict__ hist,
                            const float* __restrict__ hist_u,
                            const float* __restrict__ pred,
                            const float* __restrict__ pred_u,
                            const float* __restrict__ kw,
                            const float* __restrict__ vw,
                            const float* __restrict__ w1,
                            const float* __restrict__ w2,
                            const float* __restrict__ w3,
                            const float* __restrict__ ds_w,
                            const float* __restrict__ de_w,
                            const float* __restrict__ key_b,
                            const float* __restrict__ val_b,
                            __bf16* __restrict__ ki,
                            __bf16* __restrict__ kvwt,
                            __bf16* __restrict__ ffwt,
                            __bf16* __restrict__ ds_wt,
                            __bf16* __restrict__ de_wt,
                            float* __restrict__ kvb,
                            float* __restrict__ outz) {
  int i = blockIdx.x * 256 + threadIdx.x;
  if (i < kP1) {
    int d = i % kKP;
    int bw = i / kKP;
    int w = bw % kW;
    int b = bw / kW;
    float v = 0.f;
    if (d < 257) {
      if (w < kNH)
        v = (d < kD) ? hist[((size_t)b * kNH + w) * kD + d] : hist_u[b * kNH + w];
      else {
        int p = w - kNH;
        v = (d < kD) ? pred[((size_t)b * kNV + p) * kD + d] : pred_u[b * kNV + p];
      }
    }
    ki[i] = (__bf16)v;
  } else if (i < kP1 + kP2) {
    int j = i - kP1;
    int d = j % kKP;
    int c = j / kKP;
    float v = 0.f;
    if (d < 257) {
      bool isv = c >= 2048;
      int cc = isv ? c - 2048 : c;
      int l = cc >> 9, rest = cc & 511;
      int h = rest >> 6, a = rest & 63;
      size_t src = (((size_t)l * kH + h) * 257 + d) * kA + a;
      v = isv ? vw[src] : kw[src];
    }
    kvwt[j] = (__bf16)v;
  } else if (i < kP1 + kP2 + kP3) {
    int j = i - kP1 - kP2;
    int k = j & 511;
    int n = (j >> 9) & 511;
    int mat = j >> 18;
    int l = mat / 3, which = mat % 3;
    const float* src = which == 0 ? w1 : which == 1 ? w2 : w3;
    ffwt[j] = (__bf16)src[((size_t)l * 512 + k) * 512 + n];
  } else if (i < kP1 + kP2 + kP3 + kP4) {
    int j = i - kP1 - kP2 - kP3;
    if (j < 131072) {
      int n = j >> 8, k = j & 255;
      ds_wt[j] = (__bf16)ds_w[k * 512 + n];
    } else if (j < 196608) {
      int jj = j - 131072;
      int n = jj >> 9, k = jj & 511;
      de_wt[jj] = (__bf16)de_w[k * 128 + n];
    } else {
      int c = j - 196608;  // 0..4095
      bool isv = c >= 2048;
      int cc = isv ? c - 2048 : c;
      int l = cc >> 9, rest = cc & 511;
      kvb[c] = isv ? val_b[l * 512 + rest] : key_b[l * 512 + rest];
    }
  } else if (i < kPT) {
    outz[i - kP1 - kP2 - kP3 - kP4] = 0.f;
  }
}

// ---------------- 64x64-tile bf16 MFMA GEMM core (2-phase prefetch) ----------
// 4 waves; wave w owns rows [16w,16w+16) x all 64 cols (4 MFMA/K-step).
// Small tile -> small LDS (16-17 KB) -> 4+ blocks/CU for TLP latency hiding.
// OMODE: 1=bf16 out, 2=f32+bf16 out. XOR-swizzled staging, coalesced epilogue.
// KIMAP: A rows remap r -> (r>>8)*768 + 512 + (r&255). BIASROW: bias by row.
// Sm elems: OMODE1: max(8192 stage, 64*72=4608) = 8192
//           OMODE2: max(8192, 64*68 f32 = 8704) = 8704
template <int OMODE, bool RELU, bool KIMAP, bool BIASROW>
__device__ __forceinline__ void gemm_core64(
    int bxv, int byv, const __bf16* __restrict__ A,
    const __bf16* __restrict__ Bt, const float* __restrict__ bias,
    void* __restrict__ Cout, __bf16* __restrict__ Cout2, int K, int lda,
    int ldc, __bf16* Sm) {
  const int t = threadIdx.x;
  const int w = t >> 6;
  const int lane = t & 63;
  const int bm = byv * 64;
  const int bn = bxv * 64;
  const int sr = lane >> 2, sc = lane & 3;
  const int skey = (sr >> 1) & 3;
  const int abase = KIMAP ? ((bm >> 8) * 768 + 512 + (bm & 255)) : bm;
  const __bf16* Ag = A + (size_t)(abase + w * 16 + sr) * lda + (sc ^ skey) * 8;
  const __bf16* Bg = Bt + (size_t)(bn + w * 16 + sr) * K + (sc ^ skey) * 8;
  __bf16* A0 = Sm;
  __bf16* B0 = Sm + 2048;
  __bf16* A1 = Sm + 4096;
  __bf16* B1 = Sm + 6144;

  auto stage = [&](int k0, __bf16* As, __bf16* Bs) {
    load_lds16(Ag + k0, As + w * 512);
    load_lds16(Bg + k0, Bs + w * 512);
  };

  f32x4 acc[4] = {};
  const int q = lane >> 4, mr = lane & 15;
  const int rkey = (mr >> 1) & 3;
  stage(0, A0, B0);
  __syncthreads();
  for (int k0 = 0; k0 < K; k0 += 32) {
    if (k0 + 32 < K) stage(k0 + 32, A1, B1);  // prefetch overlaps compute
    bf16x8 af = *(const bf16x8*)(A0 + (w * 16 + mr) * 32 + (q ^ rkey) * 8);
    bf16x8 bfr[4];
#pragma unroll
    for (int j = 0; j < 4; ++j)
      bfr[j] = *(const bf16x8*)(B0 + (j * 16 + mr) * 32 + (q ^ rkey) * 8);
#pragma unroll
    for (int j = 0; j < 4; ++j)
      acc[j] = __builtin_amdgcn_mfma_f32_16x16x32_bf16(af, bfr[j], acc[j], 0,
                                                       0, 0);
    __syncthreads();  // prefetch landed; all waves done with A0/B0
    __bf16* tp = A0; A0 = A1; A1 = tp;
    tp = B0; B0 = B1; B1 = tp;
  }
  // ---- epilogue: stage C in LDS, coalesced write-out ----
  if (OMODE == 1) {
    constexpr int PS = 72;
    __bf16* Cs = Sm;  // full smem reuse (post-barrier)
#pragma unroll
    for (int j = 0; j < 4; ++j) {
      float bscol = BIASROW ? 0.f : bias[bn + j * 16 + mr];
#pragma unroll
      for (int r = 0; r < 4; ++r) {
        float v = acc[j][r] +
                  (BIASROW ? bias[bm + w * 16 + q * 4 + r] : bscol);
        if (RELU) v = fmaxf(v, 0.f);
        Cs[(w * 16 + q * 4 + r) * PS + j * 16 + mr] = (__bf16)v;
      }
    }
    __syncthreads();
    const int rl = lane >> 3, cl = (lane & 7) * 8;
#pragma unroll
    for (int it = 0; it < 2; ++it) {
      int row = w * 16 + it * 8 + rl;
      bf16x8 v = *(const bf16x8*)&Cs[row * PS + cl];
      *(bf16x8*)((__bf16*)Cout + (size_t)(bm + row) * ldc + bn + cl) = v;
    }
  } else {
    // OMODE==2: f32 staged once, dual coalesced output (f32 + bf16).
    constexpr int PSF = 68;
    float* Csf = (float*)Sm;
#pragma unroll
    for (int j = 0; j < 4; ++j) {
      float bscol = bias[bn + j * 16 + mr];
#pragma unroll
      for (int r = 0; r < 4; ++r) {
        float v = acc[j][r] + bscol;
        if (RELU) v = fmaxf(v, 0.f);
        Csf[(w * 16 + q * 4 + r) * PSF + j * 16 + mr] = v;
      }
    }
    __syncthreads();
    const int rl = lane >> 4, cl = (lane & 15) * 4;
#pragma unroll
    for (int it = 0; it < 4; ++it) {
      int row = w * 16 + it * 4 + rl;
      f32x4 v = *(const f32x4*)&Csf[row * PSF + cl];
      size_t gidx = (size_t)(bm + row) * ldc + bn + cl;
      *(f32x4*)((float*)Cout + gidx) = v;
      bf16x4 vb = {(__bf16)v[0], (__bf16)v[1], (__bf16)v[2], (__bf16)v[3]};
      *(bf16x4*)(Cout2 + gidx) = vb;
    }
  }
}

// ------------- fused ds + keys + vT GEMM (one launch, 12800 blocks) ----------
__global__ __launch_bounds__(256, 4) void gemm3_kernel(
    const __bf16* __restrict__ ki, const __bf16* __restrict__ ds_wt,
    const float* __restrict__ ds_b, float* __restrict__ att,
    __bf16* __restrict__ att_bf, const __bf16* __restrict__ kv_wt,
    const float* __restrict__ kvb, __bf16* __restrict__ kvs_k,
    __bf16* __restrict__ vT) {
  __shared__ __bf16 smem[8704];  // stage dbuf 8192; OMODE2 epilogue 8704
  // XCD-aware swizzle (12800 % 8 == 0 -> bijective)
  int bid = (blockIdx.x & 7) * 1600 + (blockIdx.x >> 3);
  if (bid < 512) {
    // ds: att(+bf) = pred @ ds_w + b  [4096 x 512], K=256, A rows inside ki
    gemm_core64<2, false, true, false>(bid & 7, bid >> 3, ki, ds_wt, ds_b, att,
                                       att_bf, 256, kKP, 512, smem);
  } else if (bid < 6656) {
    // keys: [12288 x 2048]
    int b2 = bid - 512;
    gemm_core64<1, false, false, false>(b2 & 31, b2 >> 5, ki, kv_wt, kvb,
                                        kvs_k, nullptr, kKP, kKP, 2048, smem);
  } else {
    // values^T: [2048 x 12288] = Wv^T @ ki^T (bias per row)
    int b3 = bid - 6656;
    gemm_core64<1, false, false, true>(b3 % 192, b3 / 192,
                                       kv_wt + (size_t)2048 * kKP, ki,
                                       kvb + 2048, vT, nullptr, kKP, kKP,
                                       12288, smem);
  }
}

// ---------------- ff GEMMs (gemm_core64 wrappers, grid 8x64) ----------------
template <bool RELU>
__global__ __launch_bounds__(256, 4) void gemm_ff_kernel(
    const __bf16* __restrict__ A, const __bf16* __restrict__ Bt,
    const float* __restrict__ bias, __bf16* __restrict__ Cout) {
  __shared__ __bf16 smem[8192];
  gemm_core64<1, RELU, false, false>(blockIdx.x, blockIdx.y, A, Bt, bias, Cout,
                                     nullptr, 512, 512, 512, smem);
}

// ---------------- MFMA flash attention (S^T variant, reg-prefetched) --------
__global__ __launch_bounds__(256) void attn_mfma_kernel(
    const __bf16* __restrict__ attbf, const __bf16* __restrict__ kvs_k,
    const __bf16* __restrict__ vT, __bf16* __restrict__ outbf, int l) {
  const int b = blockIdx.z, h = blockIdx.y, qt = blockIdx.x;
  __shared__ __bf16 Ks[64 * 72];
  __shared__ __bf16 Vt[64 * 72];
  __shared__ __bf16 Ps[64 * 72];
  const int t = threadIdx.x;
  const int w = t >> 6, lane = t & 63;
  const int quad = lane >> 4, mr = lane & 15;
  bf16x8 aq[2];
  {
    const __bf16* qp = attbf + ((size_t)(b * kNV + qt * 64 + w * 16 + mr) * kHA +
                                h * kA + quad * 8);
    aq[0] = *(const bf16x8*)qp;
    aq[1] = *(const bf16x8*)(qp + 32);
  }
  f32x4 o[4] = {};
  float m_ = -1e30f, l_ = 0.f;
  const int cmax = kNH + qt * 64;
  const int pr = t >> 2, pc = t & 3;
  const __bf16* kbase = kvs_k + ((size_t)(b * kW + pr) * 2048 + l * 512 + h * kA);
  const __bf16* vbase = vT + (size_t)(l * 512 + h * kA + pr) * 12288 + b * kW;
  bf16x8 kc0, kc1, vc0, vc1;
  kc0 = *(const bf16x8*)(kbase + pc * 8);
  kc1 = *(const bf16x8*)(kbase + pc * 8 + 32);
  vc0 = *(const bf16x8*)(vbase + pc * 16);
  vc1 = *(const bf16x8*)(vbase + pc * 16 + 8);
  for (int c0 = 0; c0 <= cmax; c0 += 64) {
    __syncthreads();
    *(bf16x8*)&Ks[pr * 72 + pc * 8] = kc0;
    *(bf16x8*)&Ks[pr * 72 + pc * 8 + 32] = kc1;
    *(bf16x8*)&Vt[pr * 72 + pc * 16] = vc0;
    *(bf16x8*)&Vt[pr * 72 + pc * 16 + 8] = vc1;
    __syncthreads();
    if (c0 + 64 <= cmax) {
      const __bf16* kp = kbase + (size_t)(c0 + 64) * 2048;
      const __bf16* vp = vbase + c0 + 64;
      kc0 = *(const bf16x8*)(kp + pc * 8);
      kc1 = *(const bf16x8*)(kp + pc * 8 + 32);
      vc0 = *(const bf16x8*)(vp + pc * 16);
      vc1 = *(const bf16x8*)(vp + pc * 16 + 8);
    }
    // ---- S^T = K·Q^T ----
    f32x4 s[4];
#pragma unroll
    for (int j = 0; j < 4; ++j) {
      bf16x8 ak0 = *(const bf16x8*)&Ks[(j * 16 + mr) * 72 + quad * 8];
      bf16x8 ak1 = *(const bf16x8*)&Ks[(j * 16 + mr) * 72 + quad * 8 + 32];
      f32x4 z = {};
      z = __builtin_amdgcn_mfma_f32_16x16x32_bf16(ak0, aq[0], z, 0, 0, 0);
      z = __builtin_amdgcn_mfma_f32_16x16x32_bf16(ak1, aq[1], z, 0, 0, 0);
      s[j] = z;
    }
    const int lim = cmax - c0;
    float sv[16], mx = -1e30f;
#pragma unroll
    for (int j = 0; j < 4; ++j)
#pragma unroll
      for (int r = 0; r < 4; ++r) {
        int p = j * 16 + quad * 4 + r;
        float x = (p < lim + mr) ? s[j][r] * 0.125f : -1e30f;
        sv[j * 4 + r] = x;
        mx = fmaxf(mx, x);
      }
    mx = fmaxf(mx, __shfl_xor(mx, 16));
    mx = fmaxf(mx, __shfl_xor(mx, 32));
    float mnew = fmaxf(m_, mx);
    float corr = __expf(m_ - mnew);
    float rs = 0.f;
#pragma unroll
    for (int i = 0; i < 16; ++i) {
      sv[i] = __expf(sv[i] - mnew);
      rs += sv[i];
    }
    rs += __shfl_xor(rs, 16);
    rs += __shfl_xor(rs, 32);
    l_ = l_ * corr + rs;
    m_ = mnew;
#pragma unroll
    for (int j = 0; j < 4; ++j) {
      bf16x4 pk = {(__bf16)sv[j * 4 + 0], (__bf16)sv[j * 4 + 1],
                   (__bf16)sv[j * 4 + 2], (__bf16)sv[j * 4 + 3]};
      *(bf16x4*)&Ps[(w * 16 + mr) * 72 + j * 16 + quad * 4] = pk;
    }
#pragma unroll
    for (int r = 0; r < 4; ++r) {
      float cr = __shfl(corr, quad * 4 + r);
#pragma unroll
      for (int j = 0; j < 4; ++j) o[j][r] *= cr;
    }
    bf16x8 ap0 = *(const bf16x8*)&Ps[(w * 16 + mr) * 72 + quad * 8];
    bf16x8 ap1 = *(const bf16x8*)&Ps[(w * 16 + mr) * 72 + quad * 8 + 32];
#pragma unroll
    for (int j = 0; j < 4; ++j) {
      bf16x8 b0 = *(const bf16x8*)&Vt[(j * 16 + mr) * 72 + quad * 8];
      bf16x8 b1 = *(const bf16x8*)&Vt[(j * 16 + mr) * 72 + quad * 8 + 32];
      o[j] = __builtin_amdgcn_mfma_f32_16x16x32_bf16(ap0, b0, o[j], 0, 0, 0);
      o[j] = __builtin_amdgcn_mfma_f32_16x16x32_bf16(ap1, b1, o[j], 0, 0, 0);
    }
  }
  float invl = 1.f / l_;
#pragma unroll
  for (int r = 0; r < 4; ++r) {
    float ir = __shfl(invl, quad * 4 + r);
    int row = b * kNV + qt * 64 + w * 16 + quad * 4 + r;
#pragma unroll
    for (int j = 0; j < 4; ++j)
      outbf[(size_t)row * kHA + h * kA + j * 16 + mr] = (__bf16)(o[j][r] * ir);
  }
}

// ---------------- att = LN(att + add_bf); emits bf16 copy ----------------
__global__ __launch_bounds__(128) void add_ln_kernel(
    float* __restrict__ att, const __bf16* __restrict__ addbf,
    const float* __restrict__ g, const float* __restrict__ be,
    __bf16* __restrict__ attbf) {
  const int row = blockIdx.x;
  const int t = threadIdx.x;
  float4* ar = (float4*)(att + (size_t)row * kHA);
  bf16x4 dv = *(const bf16x4*)(addbf + (size_t)row * kHA + t * 4);
  float4 x = ar[t];
  x.x += (float)dv[0]; x.y += (float)dv[1];
  x.z += (float)dv[2]; x.w += (float)dv[3];
  float s = x.x + x.y + x.z + x.w;
  float sq = x.x * x.x + x.y * x.y + x.z * x.z + x.w * x.w;
  for (int o = 32; o; o >>= 1) {
    s += __shfl_xor(s, o);
    sq += __shfl_xor(sq, o);
  }
  __shared__ float red[4];
  if ((t & 63) == 0) { red[(t >> 6) * 2] = s; red[(t >> 6) * 2 + 1] = sq; }
  __syncthreads();
  float S = red[0] + red[2], Q = red[1] + red[3];
  float mean = S * (1.f / kHA);
  float inv = rsqrtf(Q * (1.f / kHA) - mean * mean + 1e-5f);
  float4 gv = ((const float4*)g)[t];
  float4 bv = ((const float4*)be)[t];
  float4 y;
  y.x = gv.x * (x.x - mean) * inv + bv.x;
  y.y = gv.y * (x.y - mean) * inv + bv.y;
  y.z = gv.z * (x.z - mean) * inv + bv.z;
  y.w = gv.w * (x.w - mean) * inv + bv.w;
  ar[t] = y;
  bf16x4 yb = {(__bf16)y.x, (__bf16)y.y, (__bf16)y.z, (__bf16)y.w};
  *(bf16x4*)(attbf + (size_t)row * kHA + t * 4) = yb;
}

// ---------------- fused de-projection + loss (atomic into out) ----------------
__global__ __launch_bounds__(256) void de_loss_kernel(
    const __bf16* __restrict__ attbf, const __bf16* __restrict__ de_wt,
    const float* __restrict__ de_b, const float* __restrict__ pred_u,
    float* __restrict__ out) {
  const int blk = blockIdx.x;
  const int t = threadIdx.x;
  const int w = t >> 6, lane = t & 63, quad = lane >> 4, mr = lane & 15;
  const int row0 = blk * 64 + w * 16;
  f32x4 acc[8] = {};
  const __bf16* Ap = attbf + (size_t)(row0 + mr) * kHA + quad * 8;
#pragma unroll 4
  for (int k0 = 0; k0 < 512; k0 += 32) {
    bf16x8 a = *(const bf16x8*)(Ap + k0);
#pragma unroll
    for (int j = 0; j < 8; ++j) {
      bf16x8 bb =
          *(const bf16x8*)(de_wt + (size_t)(j * 16 + mr) * 512 + k0 + quad * 8);
      acc[j] = __builtin_amdgcn_mfma_f32_16x16x32_bf16(a, bb, acc[j], 0, 0, 0);
    }
  }
  float dbv[8];
#pragma unroll
  for (int j = 0; j < 8; ++j) dbv[j] = de_b[j * 16 + mr];
  float lpacc = 0.f;
#pragma unroll
  for (int r = 0; r < 4; ++r) {
    int row = row0 + quad * 4 + r;
    int v = row & 255;
    float lg[8], mx = -1e30f;
#pragma unroll
    for (int j = 0; j < 8; ++j) {
      lg[j] = acc[j][r] + dbv[j];
      mx = fmaxf(mx, lg[j]);
    }
    mx = fmaxf(mx, __shfl_xor(mx, 1));
    mx = fmaxf(mx, __shfl_xor(mx, 2));
    mx = fmaxf(mx, __shfl_xor(mx, 4));
    mx = fmaxf(mx, __shfl_xor(mx, 8));
    float se = 0.f;
#pragma unroll
    for (int j = 0; j < 8; ++j) se += __expf(lg[j] - mx);
    se += __shfl_xor(se, 1);
    se += __shfl_xor(se, 2);
    se += __shfl_xor(se, 4);
    se += __shfl_xor(se, 8);
    float lse = mx + __logf(se);
    float u = pred_u[(row >> 8) * 256 + v];
    int tgt = (int)floorf(u * 128.f);
    tgt = max(0, min(127, tgt));
    float cand = (mr == (tgt & 15)) ? lg[tgt >> 4] : 0.f;
    cand += __shfl_xor(cand, 1);
    cand += __shfl_xor(cand, 2);
    cand += __shfl_xor(cand, 4);
    cand += __shfl_xor(cand, 8);
    float lp = (v >= 1) ? (4.8520302639196171f + cand - lse) : 0.f;  // ln(128)
    lpacc += lp;
  }
  lpacc += __shfl_xor(lpacc, 16);
  lpacc += __shfl_xor(lpacc, 32);
  __shared__ float red[4];
  if (lane == 0) red[w] = lpacc;
  __syncthreads();
  if (t == 0)
    atomicAdd(&out[blk >> 2], -(red[0] + red[1] + red[2] + red[3]));
}

extern "C" void kernel_launch(void* const* d_in, const int* in_sizes, int n_in,
                              void* d_out, int out_size, void* d_ws, size_t ws_size,
                              hipStream_t stream) {
  const float* hist   = (const float*)d_in[0];
  const float* hist_u = (const float*)d_in[1];
  const float* pred   = (const float*)d_in[2];
  const float* pred_u = (const float*)d_in[3];
  const float* ds_w   = (const float*)d_in[4];
  const float* ds_b   = (const float*)d_in[5];
  const float* key_w  = (const float*)d_in[6];
  const float* key_b  = (const float*)d_in[7];
  const float* val_w  = (const float*)d_in[8];
  const float* val_b  = (const float*)d_in[9];
  const float* ln1_g  = (const float*)d_in[10];
  const float* ln1_b  = (const float*)d_in[11];
  const float* ln2_g  = (const float*)d_in[12];
  const float* ln2_b  = (const float*)d_in[13];
  const float* ff_w1  = (const float*)d_in[14];
  const float* ff_b1  = (const float*)d_in[15];
  const float* ff_w2  = (const float*)d_in[16];
  const float* ff_b2  = (const float*)d_in[17];
  const float* ff_w3  = (const float*)d_in[18];
  const float* ff_b3  = (const float*)d_in[19];
  const float* de_w   = (const float*)d_in[20];
  const float* de_b   = (const float*)d_in[21];
  float* out = (float*)d_out;

  char* ws = (char*)d_ws;
  size_t off = 0;
  auto alloc = [&](size_t bytes) { char* p = ws + off; off += bytes; return p; };
  __bf16* ki_bf  = (__bf16*)alloc((size_t)kB * kW * kKP * 2);       // 7.1 MB
  __bf16* kv_wt  = (__bf16*)alloc((size_t)4096 * kKP * 2);          // 2.4 MB
  __bf16* ffw_t  = (__bf16*)alloc((size_t)12 * 512 * 512 * 2);      // 6.3 MB
  __bf16* ds_wt  = (__bf16*)alloc((size_t)512 * 256 * 2);
  __bf16* de_wt  = (__bf16*)alloc((size_t)128 * 512 * 2);
  float*  kvb    = (float*)alloc((size_t)4096 * 4);
  __bf16* kvs_k  = (__bf16*)alloc((size_t)kB * kW * 2048 * 2);      // 50.3 MB
  __bf16* vT     = (__bf16*)alloc((size_t)2048 * 12288 * 2);        // 50.3 MB
  float*  att    = (float*)alloc((size_t)kRows * kHA * 4);          // 8.4 MB
  __bf16* att_bf = (__bf16*)alloc((size_t)kRows * kHA * 2);
  __bf16* tmp_bf = (__bf16*)alloc((size_t)kRows * kHA * 2);
  __bf16* ff1_bf = (__bf16*)alloc((size_t)kRows * kM * 2);
  __bf16* ff2_bf = (__bf16*)alloc((size_t)kRows * kM * 2);

  prep_kernel<<<(kPT + 255) / 256, 256, 0, stream>>>(
      hist, hist_u, pred, pred_u, key_w, val_w, ff_w1, ff_w2, ff_w3, ds_w, de_w,
      key_b, val_b, ki_bf, kv_wt, ffw_t, ds_wt, de_wt, kvb, out);

  // ds + keys + vT in one launch (64x64 tiles, XCD-swizzled)
  gemm3_kernel<<<12800, 256, 0, stream>>>(ki_bf, ds_wt, ds_b, att, att_bf,
                                          kv_wt, kvb, kvs_k, vT);

  for (int l = 0; l < kL; ++l) {
    attn_mfma_kernel<<<dim3(kNV / 64, kH, kB), 256, 0, stream>>>(
        att_bf, kvs_k, vT, tmp_bf, l);
    add_ln_kernel<<<kRows, 128, 0, stream>>>(att, tmp_bf, ln1_g + l * kHA,
                                             ln1_b + l * kHA, att_bf);
    gemm_ff_kernel<true><<<dim3(kM / 64, kRows / 64), 256, 0, stream>>>(
        att_bf, ffw_t + (size_t)(l * 3) * 262144, ff_b1 + l * kM, ff1_bf);
    gemm_ff_kernel<true><<<dim3(kM / 64, kRows / 64), 256, 0, stream>>>(
        ff1_bf, ffw_t + (size_t)(l * 3 + 1) * 262144, ff_b2 + l * kM, ff2_bf);
    gemm_ff_kernel<false><<<dim3(kHA / 64, kRows / 64), 256, 0, stream>>>(
        ff2_bf, ffw_t + (size_t)(l * 3 + 2) * 262144, ff_b3 + l * kHA, tmp_bf);
    add_ln_kernel<<<kRows, 128, 0, stream>>>(att, tmp_bf, ln2_g + l * kHA,
                                             ln2_b + l * kHA, att_bf);
  }
  de_loss_kernel<<<64, 256, 0, stream>>>(att_bf, de_wt, de_b, pred_u, out);
}

// Round 6
// 463.119 us; speedup vs baseline: 1.0715x; 1.0715x over previous
//
#include <hip/hip_runtime.h>

// Problem constants (AttentionalCopula)
constexpr int kB = 16, kD = 256, kNH = 512, kNV = 256, kW = 768;
constexpr int kL = 4, kH = 8, kA = 64, kHA = 512, kM = 512, kR = 128;
constexpr int kKP = 288;  // K=257 zero-padded to multiple of 32
constexpr int kRows = kB * kNV;  // 4096

typedef __bf16 bf16x8 __attribute__((ext_vector_type(8)));
typedef __bf16 bf16x4 __attribute__((ext_vector_type(4)));
typedef float f32x4 __attribute__((ext_vector_type(4)));

__device__ inline void load_lds16(const __bf16* g, __bf16* l) {
  __builtin_amdgcn_global_load_lds(
      (const __attribute__((address_space(1))) void*)g,
      (__attribute__((address_space(3))) void*)l, 16, 0, 0);
}

// ---------------- merged prep kernel (1 launch) ----------------
constexpr int kP1 = kB * kW * kKP;        // ki
constexpr int kP2 = 4096 * kKP;           // kv weights
constexpr int kP3 = 12 * 512 * 512;       // ff weights
constexpr int kP4 = 200704;               // ds_wt, de_wt, kvb
constexpr int kP5 = 16;                   // zero d_out
constexpr int kPT = kP1 + kP2 + kP3 + kP4 + kP5;

__global__ void prep_kernel(const float* __restrict__ hist,
                            const float* __restrict__ hist_u,
                            const float* __restrict__ pred,
                            const float* __restrict__ pred_u,
                            const float* __restrict__ kw,
                            const float* __restrict__ vw,
                            const float* __restrict__ w1,
                            const float* __restrict__ w2,
                            const float* __restrict__ w3,
                            const float* __restrict__ ds_w,
                            const float* __restrict__ de_w,
                            const float* __restrict__ key_b,
                            const float* __restrict__ val_b,
                            __bf16* __restrict__ ki,
                            __bf16* __restrict__ kvwt,
                            __bf16* __restrict__ ffwt,
                            __bf16* __restrict__ ds_wt,
                            __bf16* __restrict__ de_wt,
                            float* __restrict__ kvb,
                            float* __restrict__ outz) {
  int i = blockIdx.x * 256 + threadIdx.x;
  if (i < kP1) {
    int d = i % kKP;
    int bw = i / kKP;
    int w = bw % kW;
    int b = bw / kW;
    float v = 0.f;
    if (d < 257) {
      if (w < kNH)
        v = (d < kD) ? hist[((size_t)b * kNH + w) * kD + d] : hist_u[b * kNH + w];
      else {
        int p = w - kNH;
        v = (d < kD) ? pred[((size_t)b * kNV + p) * kD + d] : pred_u[b * kNV + p];
      }
    }
    ki[i] = (__bf16)v;
  } else if (i < kP1 + kP2) {
    int j = i - kP1;
    int d = j % kKP;
    int c = j / kKP;
    float v = 0.f;
    if (d < 257) {
      bool isv = c >= 2048;
      int cc = isv ? c - 2048 : c;
      int l = cc >> 9, rest = cc & 511;
      int h = rest >> 6, a = rest & 63;
      size_t src = (((size_t)l * kH + h) * 257 + d) * kA + a;
      v = isv ? vw[src] : kw[src];
    }
    kvwt[j] = (__bf16)v;
  } else if (i < kP1 + kP2 + kP3) {
    int j = i - kP1 - kP2;
    int k = j & 511;
    int n = (j >> 9) & 511;
    int mat = j >> 18;
    int l = mat / 3, which = mat % 3;
    const float* src = which == 0 ? w1 : which == 1 ? w2 : w3;
    ffwt[j] = (__bf16)src[((size_t)l * 512 + k) * 512 + n];
  } else if (i < kP1 + kP2 + kP3 + kP4) {
    int j = i - kP1 - kP2 - kP3;
    if (j < 131072) {
      int n = j >> 8, k = j & 255;
      ds_wt[j] = (__bf16)ds_w[k * 512 + n];
    } else if (j < 196608) {
      int jj = j - 131072;
      int n = jj >> 9, k = jj & 511;
      de_wt[jj] = (__bf16)de_w[k * 128 + n];
    } else {
      int c = j - 196608;  // 0..4095
      bool isv = c >= 2048;
      int cc = isv ? c - 2048 : c;
      int l = cc >> 9, rest = cc & 511;
      kvb[c] = isv ? val_b[l * 512 + rest] : key_b[l * 512 + rest];
    }
  } else if (i < kPT) {
    outz[i - kP1 - kP2 - kP3 - kP4] = 0.f;
  }
}

// ---------------- generic bf16 MFMA GEMM core (2-phase prefetch) ----------------
// OMODE: 1=bf16 out, 2=f32+bf16 out. XOR-swizzled LDS staging for A/B.
// Double-buffered staging, single barrier per K-step. Coalesced LDS epilogue.
// KIMAP: A rows remap r -> (r>>8)*768 + 512 + (r&255). BIASROW: bias by row.
template <int BN, int OMODE, bool RELU, bool KIMAP, bool BIASROW>
__device__ __forceinline__ void gemm_core(
    int bxv, int byv, const __bf16* __restrict__ A,
    const __bf16* __restrict__ Bt, const float* __restrict__ bias,
    void* __restrict__ Cout, __bf16* __restrict__ Cout2, int K, int lda,
    int ldc, __bf16* Sm) {
  constexpr int JN = BN / 32;
  constexpr int BROWS = BN / 4;
  constexpr int SSTEP = (128 + BN) * 32;  // one stage buffer, bf16 elems
  const int t = threadIdx.x;
  const int wid = t >> 6;
  const int lane = t & 63;
  const int bm = byv * 128;
  const int bn = bxv * BN;
  const int wm = (wid >> 1) * 64;
  const int wn = (wid & 1) * (BN / 2);
  const int sr = lane >> 2, sc = lane & 3;
  const int skey = (sr >> 1) & 3;
  const int abase = KIMAP ? ((bm >> 8) * 768 + 512 + (bm & 255)) : bm;
  const __bf16* Ag = A + (size_t)(abase + wid * 32 + sr) * lda + (sc ^ skey) * 8;
  const __bf16* Bg = Bt + (size_t)(bn + wid * BROWS + sr) * K + (sc ^ skey) * 8;
  __bf16* A0 = Sm;
  __bf16* B0 = Sm + 4096;
  __bf16* A1 = Sm + SSTEP;
  __bf16* B1 = Sm + SSTEP + 4096;

  auto stage = [&](int k0, __bf16* As, __bf16* Bs) {
    load_lds16(Ag + k0, As + (wid * 32) * 32);
    load_lds16(Ag + (size_t)16 * lda + k0, As + (wid * 32 + 16) * 32);
    load_lds16(Bg + k0, Bs + (wid * BROWS) * 32);
    if (BN == 128)
      load_lds16(Bg + (size_t)16 * K + k0, Bs + (wid * BROWS + 16) * 32);
  };

  f32x4 acc[4][JN] = {};
  const int q = lane >> 4, mr = lane & 15;
  const int rkey = (mr >> 1) & 3;
  stage(0, A0, B0);
  __syncthreads();
  for (int k0 = 0; k0 < K; k0 += 32) {
    if (k0 + 32 < K) stage(k0 + 32, A1, B1);  // prefetch overlaps compute
    bf16x8 af[4], bfr[JN];
#pragma unroll
    for (int i = 0; i < 4; ++i)
      af[i] = *(const bf16x8*)(A0 + (wm + i * 16 + mr) * 32 + (q ^ rkey) * 8);
#pragma unroll
    for (int j = 0; j < JN; ++j)
      bfr[j] = *(const bf16x8*)(B0 + (wn + j * 16 + mr) * 32 + (q ^ rkey) * 8);
#pragma unroll
    for (int i = 0; i < 4; ++i)
#pragma unroll
      for (int j = 0; j < JN; ++j)
        acc[i][j] = __builtin_amdgcn_mfma_f32_16x16x32_bf16(af[i], bfr[j],
                                                            acc[i][j], 0, 0, 0);
    __syncthreads();  // prefetch landed; all waves done reading A0/B0
    __bf16* tp = A0; A0 = A1; A1 = tp;
    tp = B0; B0 = B1; B1 = tp;
  }
  // ---- epilogue: stage C in LDS, coalesced write-out ----
  if (OMODE == 1) {
    constexpr int PS = BN + 8;
    __bf16* Cs = Sm;  // full smem reuse (post-barrier)
#pragma unroll
    for (int j = 0; j < JN; ++j) {
      float bscol = BIASROW ? 0.f : bias[bn + wn + j * 16 + mr];
#pragma unroll
      for (int i = 0; i < 4; ++i) {
#pragma unroll
        for (int r = 0; r < 4; ++r) {
          float v = acc[i][j][r] +
                    (BIASROW ? bias[bm + wm + i * 16 + q * 4 + r] : bscol);
          if (RELU) v = fmaxf(v, 0.f);
          Cs[(wm + i * 16 + q * 4 + r) * PS + wn + j * 16 + mr] = (__bf16)v;
        }
      }
    }
    __syncthreads();
    constexpr int lpr = BN / 8;    // lanes per row (16B each)
    constexpr int rpi = 512 / BN;  // rows per wave-iteration
    const int rl = lane / lpr, cl = (lane % lpr) * 8;
#pragma unroll
    for (int it = 0; it < BN / 16; ++it) {
      int row = wid * 32 + it * rpi + rl;
      bf16x8 v = *(const bf16x8*)&Cs[row * PS + cl];
      *(bf16x8*)((__bf16*)Cout + (size_t)(bm + row) * ldc + bn + cl) = v;
    }
  } else {
    // OMODE==2: f32 staged once, dual coalesced output (f32 + bf16). BN=64.
    constexpr int PSF = BN + 4;
    float* Csf = (float*)Sm;
#pragma unroll
    for (int j = 0; j < JN; ++j) {
      float bscol = bias[bn + wn + j * 16 + mr];
#pragma unroll
      for (int i = 0; i < 4; ++i) {
#pragma unroll
        for (int r = 0; r < 4; ++r) {
          float v = acc[i][j][r] + bscol;
          if (RELU) v = fmaxf(v, 0.f);
          Csf[(wm + i * 16 + q * 4 + r) * PSF + wn + j * 16 + mr] = v;
        }
      }
    }
    __syncthreads();
    const int rl = lane >> 4, cl = (lane & 15) * 4;
#pragma unroll
    for (int it = 0; it < 8; ++it) {
      int row = wid * 32 + it * 4 + rl;
      f32x4 v = *(const f32x4*)&Csf[row * PSF + cl];
      size_t gidx = (size_t)(bm + row) * ldc + bn + cl;
      *(f32x4*)((float*)Cout + gidx) = v;
      bf16x4 vb = {(__bf16)v[0], (__bf16)v[1], (__bf16)v[2], (__bf16)v[3]};
      *(bf16x4*)(Cout2 + gidx) = vb;
    }
  }
}

// ---------------- fused ds + keys + vT GEMM (one launch, 3328 blocks) ----------------
__global__ __launch_bounds__(256) void gemm3_kernel(
    const __bf16* __restrict__ ki, const __bf16* __restrict__ ds_wt,
    const float* __restrict__ ds_b, float* __restrict__ att,
    __bf16* __restrict__ att_bf, const __bf16* __restrict__ kv_wt,
    const float* __restrict__ kvb, __bf16* __restrict__ kvs_k,
    __bf16* __restrict__ vT) {
  __shared__ __bf16 smem[17408];  // dbuf staging 16384; epilogue 17408
  // XCD chunked swizzle (3328 = 8*416, bijective): each XCD gets a
  // contiguous 416-block chunk -> same-A-panel neighbors share L2.
  int bid = (blockIdx.x & 7) * 416 + (blockIdx.x >> 3);
  if (bid < 256) {
    // ds: att(+bf) = pred @ ds_w + b  [4096 x 512], K=256, A rows inside ki
    gemm_core<64, 2, false, true, false>(bid & 7, bid >> 3, ki, ds_wt, ds_b,
                                         att, att_bf, 256, kKP, 512, smem);
  } else if (bid < 1792) {
    // keys: [12288 x 2048]
    int b2 = bid - 256;
    gemm_core<128, 1, false, false, false>(b2 & 15, b2 >> 4, ki, kv_wt, kvb,
                                           kvs_k, nullptr, kKP, kKP, 2048,
                                           smem);
  } else {
    // values^T: [2048 x 12288] = Wv^T @ ki^T (bias per row)
    int b3 = bid - 1792;
    gemm_core<128, 1, false, false, true>(b3 % 96, b3 / 96,
                                          kv_wt + (size_t)2048 * kKP, ki,
                                          kvb + 2048, vT, nullptr, kKP, kKP,
                                          12288, smem);
  }
}

// ---------------- ff GEMMs (gemm_core wrappers) ----------------
template <bool RELU>
__global__ __launch_bounds__(256) void gemm_ff_kernel(
    const __bf16* __restrict__ A, const __bf16* __restrict__ Bt,
    const float* __restrict__ bias, __bf16* __restrict__ Cout) {
  __shared__ __bf16 smem[12288];  // dbuf staging 12288; epilogue 9216
  gemm_core<64, 1, RELU, false, false>(blockIdx.x, blockIdx.y, A, Bt, bias,
                                       Cout, nullptr, 512, 512, 512, smem);
}

// ---------------- MFMA flash attention (S^T variant, reg-prefetched) --------
// 1-D grid of 512 blocks, XCD-pinned: id&7 == b&7, so all 32 (qt,h) blocks
// of a batch run on one XCD -> K/V working set (~3 MB for 2 batches) is
// L2-resident instead of re-fetched from HBM by every XCD.
__global__ __launch_bounds__(256) void attn_mfma_kernel(
    const __bf16* __restrict__ attbf, const __bf16* __restrict__ kvs_k,
    const __bf16* __restrict__ vT, __bf16* __restrict__ outbf, int l) {
  const int id = blockIdx.x;
  const int kk = id >> 3;
  const int b = ((kk >> 5) << 3) | (id & 7);
  const int qt = kk & 3;
  const int h = (kk >> 2) & 7;
  __shared__ __bf16 Ks[64 * 72];
  __shared__ __bf16 Vt[64 * 72];
  __shared__ __bf16 Ps[64 * 72];
  const int t = threadIdx.x;
  const int w = t >> 6, lane = t & 63;
  const int quad = lane >> 4, mr = lane & 15;
  bf16x8 aq[2];
  {
    const __bf16* qp = attbf + ((size_t)(b * kNV + qt * 64 + w * 16 + mr) * kHA +
                                h * kA + quad * 8);
    aq[0] = *(const bf16x8*)qp;
    aq[1] = *(const bf16x8*)(qp + 32);
  }
  f32x4 o[4] = {};
  float m_ = -1e30f, l_ = 0.f;
  const int cmax = kNH + qt * 64;
  const int pr = t >> 2, pc = t & 3;
  const __bf16* kbase = kvs_k + ((size_t)(b * kW + pr) * 2048 + l * 512 + h * kA);
  const __bf16* vbase = vT + (size_t)(l * 512 + h * kA + pr) * 12288 + b * kW;
  bf16x8 kc0, kc1, vc0, vc1;
  kc0 = *(const bf16x8*)(kbase + pc * 8);
  kc1 = *(const bf16x8*)(kbase + pc * 8 + 32);
  vc0 = *(const bf16x8*)(vbase + pc * 16);
  vc1 = *(const bf16x8*)(vbase + pc * 16 + 8);
  for (int c0 = 0; c0 <= cmax; c0 += 64) {
    __syncthreads();
    *(bf16x8*)&Ks[pr * 72 + pc * 8] = kc0;
    *(bf16x8*)&Ks[pr * 72 + pc * 8 + 32] = kc1;
    *(bf16x8*)&Vt[pr * 72 + pc * 16] = vc0;
    *(bf16x8*)&Vt[pr * 72 + pc * 16 + 8] = vc1;
    __syncthreads();
    if (c0 + 64 <= cmax) {
      const __bf16* kp = kbase + (size_t)(c0 + 64) * 2048;
      const __bf16* vp = vbase + c0 + 64;
      kc0 = *(const bf16x8*)(kp + pc * 8);
      kc1 = *(const bf16x8*)(kp + pc * 8 + 32);
      vc0 = *(const bf16x8*)(vp + pc * 16);
      vc1 = *(const bf16x8*)(vp + pc * 16 + 8);
    }
    // ---- S^T = K·Q^T ----
    f32x4 s[4];
#pragma unroll
    for (int j = 0; j < 4; ++j) {
      bf16x8 ak0 = *(const bf16x8*)&Ks[(j * 16 + mr) * 72 + quad * 8];
      bf16x8 ak1 = *(const bf16x8*)&Ks[(j * 16 + mr) * 72 + quad * 8 + 32];
      f32x4 z = {};
      z = __builtin_amdgcn_mfma_f32_16x16x32_bf16(ak0, aq[0], z, 0, 0, 0);
      z = __builtin_amdgcn_mfma_f32_16x16x32_bf16(ak1, aq[1], z, 0, 0, 0);
      s[j] = z;
    }
    const int lim = cmax - c0;
    float sv[16], mx = -1e30f;
#pragma unroll
    for (int j = 0; j < 4; ++j)
#pragma unroll
      for (int r = 0; r < 4; ++r) {
        int p = j * 16 + quad * 4 + r;
        float x = (p < lim + mr) ? s[j][r] * 0.125f : -1e30f;
        sv[j * 4 + r] = x;
        mx = fmaxf(mx, x);
      }
    mx = fmaxf(mx, __shfl_xor(mx, 16));
    mx = fmaxf(mx, __shfl_xor(mx, 32));
    float mnew = fmaxf(m_, mx);
    float corr = __expf(m_ - mnew);
    float rs = 0.f;
#pragma unroll
    for (int i = 0; i < 16; ++i) {
      sv[i] = __expf(sv[i] - mnew);
      rs += sv[i];
    }
    rs += __shfl_xor(rs, 16);
    rs += __shfl_xor(rs, 32);
    l_ = l_ * corr + rs;
    m_ = mnew;
#pragma unroll
    for (int j = 0; j < 4; ++j) {
      bf16x4 pk = {(__bf16)sv[j * 4 + 0], (__bf16)sv[j * 4 + 1],
                   (__bf16)sv[j * 4 + 2], (__bf16)sv[j * 4 + 3]};
      *(bf16x4*)&Ps[(w * 16 + mr) * 72 + j * 16 + quad * 4] = pk;
    }
#pragma unroll
    for (int r = 0; r < 4; ++r) {
      float cr = __shfl(corr, quad * 4 + r);
#pragma unroll
      for (int j = 0; j < 4; ++j) o[j][r] *= cr;
    }
    bf16x8 ap0 = *(const bf16x8*)&Ps[(w * 16 + mr) * 72 + quad * 8];
    bf16x8 ap1 = *(const bf16x8*)&Ps[(w * 16 + mr) * 72 + quad * 8 + 32];
#pragma unroll
    for (int j = 0; j < 4; ++j) {
      bf16x8 b0 = *(const bf16x8*)&Vt[(j * 16 + mr) * 72 + quad * 8];
      bf16x8 b1 = *(const bf16x8*)&Vt[(j * 16 + mr) * 72 + quad * 8 + 32];
      o[j] = __builtin_amdgcn_mfma_f32_16x16x32_bf16(ap0, b0, o[j], 0, 0, 0);
      o[j] = __builtin_amdgcn_mfma_f32_16x16x32_bf16(ap1, b1, o[j], 0, 0, 0);
    }
  }
  float invl = 1.f / l_;
#pragma unroll
  for (int r = 0; r < 4; ++r) {
    float ir = __shfl(invl, quad * 4 + r);
    int row = b * kNV + qt * 64 + w * 16 + quad * 4 + r;
#pragma unroll
    for (int j = 0; j < 4; ++j)
      outbf[(size_t)row * kHA + h * kA + j * 16 + mr] = (__bf16)(o[j][r] * ir);
  }
}

// ---------------- att = LN(att + add_bf); emits bf16 copy ----------------
__global__ __launch_bounds__(128) void add_ln_kernel(
    float* __restrict__ att, const __bf16* __restrict__ addbf,
    const float* __restrict__ g, const float* __restrict__ be,
    __bf16* __restrict__ attbf) {
  const int row = blockIdx.x;
  const int t = threadIdx.x;
  float4* ar = (float4*)(att + (size_t)row * kHA);
  bf16x4 dv = *(const bf16x4*)(addbf + (size_t)row * kHA + t * 4);
  float4 x = ar[t];
  x.x += (float)dv[0]; x.y += (float)dv[1];
  x.z += (float)dv[2]; x.w += (float)dv[3];
  float s = x.x + x.y + x.z + x.w;
  float sq = x.x * x.x + x.y * x.y + x.z * x.z + x.w * x.w;
  for (int o = 32; o; o >>= 1) {
    s += __shfl_xor(s, o);
    sq += __shfl_xor(sq, o);
  }
  __shared__ float red[4];
  if ((t & 63) == 0) { red[(t >> 6) * 2] = s; red[(t >> 6) * 2 + 1] = sq; }
  __syncthreads();
  float S = red[0] + red[2], Q = red[1] + red[3];
  float mean = S * (1.f / kHA);
  float inv = rsqrtf(Q * (1.f / kHA) - mean * mean + 1e-5f);
  float4 gv = ((const float4*)g)[t];
  float4 bv = ((const float4*)be)[t];
  float4 y;
  y.x = gv.x * (x.x - mean) * inv + bv.x;
  y.y = gv.y * (x.y - mean) * inv + bv.y;
  y.z = gv.z * (x.z - mean) * inv + bv.z;
  y.w = gv.w * (x.w - mean) * inv + bv.w;
  ar[t] = y;
  bf16x4 yb = {(__bf16)y.x, (__bf16)y.y, (__bf16)y.z, (__bf16)y.w};
  *(bf16x4*)(attbf + (size_t)row * kHA + t * 4) = yb;
}

// ---------------- fused de-projection + loss (atomic into out) ----------------
__global__ __launch_bounds__(256) void de_loss_kernel(
    const __bf16* __restrict__ attbf, const __bf16* __restrict__ de_wt,
    const float* __restrict__ de_b, const float* __restrict__ pred_u,
    float* __restrict__ out) {
  const int blk = blockIdx.x;
  const int t = threadIdx.x;
  const int w = t >> 6, lane = t & 63, quad = lane >> 4, mr = lane & 15;
  const int row0 = blk * 64 + w * 16;
  f32x4 acc[8] = {};
  const __bf16* Ap = attbf + (size_t)(row0 + mr) * kHA + quad * 8;
#pragma unroll 4
  for (int k0 = 0; k0 < 512; k0 += 32) {
    bf16x8 a = *(const bf16x8*)(Ap + k0);
#pragma unroll
    for (int j = 0; j < 8; ++j) {
      bf16x8 bb =
          *(const bf16x8*)(de_wt + (size_t)(j * 16 + mr) * 512 + k0 + quad * 8);
      acc[j] = __builtin_amdgcn_mfma_f32_16x16x32_bf16(a, bb, acc[j], 0, 0, 0);
    }
  }
  float dbv[8];
#pragma unroll
  for (int j = 0; j < 8; ++j) dbv[j] = de_b[j * 16 + mr];
  float lpacc = 0.f;
#pragma unroll
  for (int r = 0; r < 4; ++r) {
    int row = row0 + quad * 4 + r;
    int v = row & 255;
    float lg[8], mx = -1e30f;
#pragma unroll
    for (int j = 0; j < 8; ++j) {
      lg[j] = acc[j][r] + dbv[j];
      mx = fmaxf(mx, lg[j]);
    }
    mx = fmaxf(mx, __shfl_xor(mx, 1));
    mx = fmaxf(mx, __shfl_xor(mx, 2));
    mx = fmaxf(mx, __shfl_xor(mx, 4));
    mx = fmaxf(mx, __shfl_xor(mx, 8));
    float se = 0.f;
#pragma unroll
    for (int j = 0; j < 8; ++j) se += __expf(lg[j] - mx);
    se += __shfl_xor(se, 1);
    se += __shfl_xor(se, 2);
    se += __shfl_xor(se, 4);
    se += __shfl_xor(se, 8);
    float lse = mx + __logf(se);
    float u = pred_u[(row >> 8) * 256 + v];
    int tgt = (int)floorf(u * 128.f);
    tgt = max(0, min(127, tgt));
    float cand = (mr == (tgt & 15)) ? lg[tgt >> 4] : 0.f;
    cand += __shfl_xor(cand, 1);
    cand += __shfl_xor(cand, 2);
    cand += __shfl_xor(cand, 4);
    cand += __shfl_xor(cand, 8);
    float lp = (v >= 1) ? (4.8520302639196171f + cand - lse) : 0.f;  // ln(128)
    lpacc += lp;
  }
  lpacc += __shfl_xor(lpacc, 16);
  lpacc += __shfl_xor(lpacc, 32);
  __shared__ float red[4];
  if (lane == 0) red[w] = lpacc;
  __syncthreads();
  if (t == 0)
    atomicAdd(&out[blk >> 2], -(red[0] + red[1] + red[2] + red[3]));
}

extern "C" void kernel_launch(void* const* d_in, const int* in_sizes, int n_in,
                              void* d_out, int out_size, void* d_ws, size_t ws_size,
                              hipStream_t stream) {
  const float* hist   = (const float*)d_in[0];
  const float* hist_u = (const float*)d_in[1];
  const float* pred   = (const float*)d_in[2];
  const float* pred_u = (const float*)d_in[3];
  const float* ds_w   = (const float*)d_in[4];
  const float* ds_b   = (const float*)d_in[5];
  const float* key_w  = (const float*)d_in[6];
  const float* key_b  = (const float*)d_in[7];
  const float* val_w  = (const float*)d_in[8];
  const float* val_b  = (const float*)d_in[9];
  const float* ln1_g  = (const float*)d_in[10];
  const float* ln1_b  = (const float*)d_in[11];
  const float* ln2_g  = (const float*)d_in[12];
  const float* ln2_b  = (const float*)d_in[13];
  const float* ff_w1  = (const float*)d_in[14];
  const float* ff_b1  = (const float*)d_in[15];
  const float* ff_w2  = (const float*)d_in[16];
  const float* ff_b2  = (const float*)d_in[17];
  const float* ff_w3  = (const float*)d_in[18];
  const float* ff_b3  = (const float*)d_in[19];
  const float* de_w   = (const float*)d_in[20];
  const float* de_b   = (const float*)d_in[21];
  float* out = (float*)d_out;

  char* ws = (char*)d_ws;
  size_t off = 0;
  auto alloc = [&](size_t bytes) { char* p = ws + off; off += bytes; return p; };
  __bf16* ki_bf  = (__bf16*)alloc((size_t)kB * kW * kKP * 2);       // 7.1 MB
  __bf16* kv_wt  = (__bf16*)alloc((size_t)4096 * kKP * 2);          // 2.4 MB
  __bf16* ffw_t  = (__bf16*)alloc((size_t)12 * 512 * 512 * 2);      // 6.3 MB
  __bf16* ds_wt  = (__bf16*)alloc((size_t)512 * 256 * 2);
  __bf16* de_wt  = (__bf16*)alloc((size_t)128 * 512 * 2);
  float*  kvb    = (float*)alloc((size_t)4096 * 4);
  __bf16* kvs_k  = (__bf16*)alloc((size_t)kB * kW * 2048 * 2);      // 50.3 MB
  __bf16* vT     = (__bf16*)alloc((size_t)2048 * 12288 * 2);        // 50.3 MB
  float*  att    = (float*)alloc((size_t)kRows * kHA * 4);          // 8.4 MB
  __bf16* att_bf = (__bf16*)alloc((size_t)kRows * kHA * 2);
  __bf16* tmp_bf = (__bf16*)alloc((size_t)kRows * kHA * 2);
  __bf16* ff1_bf = (__bf16*)alloc((size_t)kRows * kM * 2);
  __bf16* ff2_bf = (__bf16*)alloc((size_t)kRows * kM * 2);

  prep_kernel<<<(kPT + 255) / 256, 256, 0, stream>>>(
      hist, hist_u, pred, pred_u, key_w, val_w, ff_w1, ff_w2, ff_w3, ds_w, de_w,
      key_b, val_b, ki_bf, kv_wt, ffw_t, ds_wt, de_wt, kvb, out);

  // ds + keys + vT in one launch
  gemm3_kernel<<<3328, 256, 0, stream>>>(ki_bf, ds_wt, ds_b, att, att_bf, kv_wt,
                                         kvb, kvs_k, vT);

  for (int l = 0; l < kL; ++l) {
    attn_mfma_kernel<<<512, 256, 0, stream>>>(att_bf, kvs_k, vT, tmp_bf, l);
    add_ln_kernel<<<kRows, 128, 0, stream>>>(att, tmp_bf, ln1_g + l * kHA,
                                             ln1_b + l * kHA, att_bf);
    gemm_ff_kernel<true><<<dim3(kM / 64, kRows / 128), 256, 0, stream>>>(
        att_bf, ffw_t + (size_t)(l * 3) * 262144, ff_b1 + l * kM, ff1_bf);
    gemm_ff_kernel<true><<<dim3(kM / 64, kRows / 128), 256, 0, stream>>>(
        ff1_bf, ffw_t + (size_t)(l * 3 + 1) * 262144, ff_b2 + l * kM, ff2_bf);
    gemm_ff_kernel<false><<<dim3(kHA / 64, kRows / 128), 256, 0, stream>>>(
        ff2_bf, ffw_t + (size_t)(l * 3 + 2) * 262144, ff_b3 + l * kHA, tmp_bf);
    add_ln_kernel<<<kRows, 128, 0, stream>>>(att, tmp_bf, ln2_g + l * kHA,
                                             ln2_b + l * kHA, att_bf);
  }
  de_loss_kernel<<<64, 256, 0, stream>>>(att_bf, de_wt, de_b, pred_u, out);
}

// Round 7
// 442.720 us; speedup vs baseline: 1.1209x; 1.0461x over previous
//
#include <hip/hip_runtime.h>

// Problem constants (AttentionalCopula)
constexpr int kB = 16, kD = 256, kNH = 512, kNV = 256, kW = 768;
constexpr int kL = 4, kH = 8, kA = 64, kHA = 512, kM = 512, kR = 128;
constexpr int kKP = 288;  // K=257 zero-padded to multiple of 32
constexpr int kRows = kB * kNV;  // 4096

typedef __bf16 bf16x8 __attribute__((ext_vector_type(8)));
typedef __bf16 bf16x4 __attribute__((ext_vector_type(4)));
typedef float f32x4 __attribute__((ext_vector_type(4)));

__device__ inline void load_lds16(const __bf16* g, __bf16* l) {
  __builtin_amdgcn_global_load_lds(
      (const __attribute__((address_space(1))) void*)g,
      (__attribute__((address_space(3))) void*)l, 16, 0, 0);
}

// ---------------- merged prep kernel (1 launch) ----------------
constexpr int kP1 = kB * kW * kKP;        // ki
constexpr int kP2 = 4096 * kKP;           // kv weights
constexpr int kP3 = 12 * 512 * 512;       // ff weights
constexpr int kP4 = 200704;               // ds_wt, de_wt, kvb
constexpr int kP5 = 16;                   // zero d_out
constexpr int kPT = kP1 + kP2 + kP3 + kP4 + kP5;

__global__ void prep_kernel(const float* __restrict__ hist,
                            const float* __restrict__ hist_u,
                            const float* __restrict__ pred,
                            const float* __restrict__ pred_u,
                            const float* __restrict__ kw,
                            const float* __restrict__ vw,
                            const float* __restrict__ w1,
                            const float* __restrict__ w2,
                            const float* __restrict__ w3,
                            const float* __restrict__ ds_w,
                            const float* __restrict__ de_w,
                            const float* __restrict__ key_b,
                            const float* __restrict__ val_b,
                            __bf16* __restrict__ ki,
                            __bf16* __restrict__ kvwt,
                            __bf16* __restrict__ ffwt,
                            __bf16* __restrict__ ds_wt,
                            __bf16* __restrict__ de_wt,
                            float* __restrict__ kvb,
                            float* __restrict__ outz) {
  int i = blockIdx.x * 256 + threadIdx.x;
  if (i < kP1) {
    int d = i % kKP;
    int bw = i / kKP;
    int w = bw % kW;
    int b = bw / kW;
    float v = 0.f;
    if (d < 257) {
      if (w < kNH)
        v = (d < kD) ? hist[((size_t)b * kNH + w) * kD + d] : hist_u[b * kNH + w];
      else {
        int p = w - kNH;
        v = (d < kD) ? pred[((size_t)b * kNV + p) * kD + d] : pred_u[b * kNV + p];
      }
    }
    ki[i] = (__bf16)v;
  } else if (i < kP1 + kP2) {
    int j = i - kP1;
    int d = j % kKP;
    int c = j / kKP;
    float v = 0.f;
    if (d < 257) {
      bool isv = c >= 2048;
      int cc = isv ? c - 2048 : c;
      int l = cc >> 9, rest = cc & 511;
      int h = rest >> 6, a = rest & 63;
      size_t src = (((size_t)l * kH + h) * 257 + d) * kA + a;
      v = isv ? vw[src] : kw[src];
    }
    kvwt[j] = (__bf16)v;
  } else if (i < kP1 + kP2 + kP3) {
    int j = i - kP1 - kP2;
    int k = j & 511;
    int n = (j >> 9) & 511;
    int mat = j >> 18;
    int l = mat / 3, which = mat % 3;
    const float* src = which == 0 ? w1 : which == 1 ? w2 : w3;
    ffwt[j] = (__bf16)src[((size_t)l * 512 + k) * 512 + n];
  } else if (i < kP1 + kP2 + kP3 + kP4) {
    int j = i - kP1 - kP2 - kP3;
    if (j < 131072) {
      int n = j >> 8, k = j & 255;
      ds_wt[j] = (__bf16)ds_w[k * 512 + n];
    } else if (j < 196608) {
      int jj = j - 131072;
      int n = jj >> 9, k = jj & 511;
      de_wt[jj] = (__bf16)de_w[k * 128 + n];
    } else {
      int c = j - 196608;  // 0..4095
      bool isv = c >= 2048;
      int cc = isv ? c - 2048 : c;
      int l = cc >> 9, rest = cc & 511;
      kvb[c] = isv ? val_b[l * 512 + rest] : key_b[l * 512 + rest];
    }
  } else if (i < kPT) {
    outz[i - kP1 - kP2 - kP3 - kP4] = 0.f;
  }
}

// ------------- generic bf16 MFMA GEMM core (3-buf counted-vmcnt pipeline) ----
// T4 pattern: distance-2 prefetch, raw s_barrier + counted s_waitcnt vmcnt(LPS)
// so the NEXT stage's global_load_lds stay in flight across the barrier
// (never drain vmcnt to 0 in the main loop). LPS = loads/wave/stage.
// OMODE: 1=bf16 out, 2=f32+bf16 out. XOR-swizzled staging, coalesced epilogue.
// KIMAP: A rows remap r -> (r>>8)*768 + 512 + (r&255). BIASROW: bias by row.
// Sm elems needed: 3*SSTEP stage vs epilogue tile:
//   BN=128 OMODE1: max(24576, 17408) = 24576
//   BN=64  OMODE2: max(18432, 17408) = 18432
//   BN=64  OMODE1: max(18432, 9216)  = 18432
template <int BN, int OMODE, bool RELU, bool KIMAP, bool BIASROW>
__device__ __forceinline__ void gemm_core(
    int bxv, int byv, const __bf16* __restrict__ A,
    const __bf16* __restrict__ Bt, const float* __restrict__ bias,
    void* __restrict__ Cout, __bf16* __restrict__ Cout2, int K, int lda,
    int ldc, __bf16* Sm) {
  constexpr int JN = BN / 32;
  constexpr int BROWS = BN / 4;
  constexpr int SSTEP = (128 + BN) * 32;       // one stage buffer, bf16 elems
  constexpr int LPS = (BN == 128) ? 4 : 3;     // global_load_lds per wave/stage
  const int t = threadIdx.x;
  const int wid = t >> 6;
  const int lane = t & 63;
  const int bm = byv * 128;
  const int bn = bxv * BN;
  const int wm = (wid >> 1) * 64;
  const int wn = (wid & 1) * (BN / 2);
  const int sr = lane >> 2, sc = lane & 3;
  const int skey = (sr >> 1) & 3;
  const int abase = KIMAP ? ((bm >> 8) * 768 + 512 + (bm & 255)) : bm;
  const __bf16* Ag = A + (size_t)(abase + wid * 32 + sr) * lda + (sc ^ skey) * 8;
  const __bf16* Bg = Bt + (size_t)(bn + wid * BROWS + sr) * K + (sc ^ skey) * 8;

  auto stage = [&](int k0, __bf16* buf) {
    __bf16* As = buf;
    __bf16* Bs = buf + 4096;
    load_lds16(Ag + k0, As + (wid * 32) * 32);
    load_lds16(Ag + (size_t)16 * lda + k0, As + (wid * 32 + 16) * 32);
    load_lds16(Bg + k0, Bs + (wid * BROWS) * 32);
    if (BN == 128)
      load_lds16(Bg + (size_t)16 * K + k0, Bs + (wid * BROWS + 16) * 32);
  };

  f32x4 acc[4][JN] = {};
  const int q = lane >> 4, mr = lane & 15;
  const int rkey = (mr >> 1) & 3;
  const int nst = K >> 5;
  __bf16* cB = Sm;               // current
  __bf16* nB = Sm + SSTEP;       // next (landed by barrier)
  __bf16* fB = Sm + 2 * SSTEP;   // being filled
  stage(0, cB);
  stage(32, nB);
  asm volatile("s_waitcnt vmcnt(%0)" ::"n"(LPS) : "memory");  // stage0 landed
  __builtin_amdgcn_s_barrier();
  for (int k = 0; k < nst; ++k) {
    if (k + 2 < nst) stage((k + 2) << 5, fB);  // fill fB while computing cB
    bf16x8 af[4], bfr[JN];
#pragma unroll
    for (int i = 0; i < 4; ++i)
      af[i] = *(const bf16x8*)(cB + (wm + i * 16 + mr) * 32 + (q ^ rkey) * 8);
#pragma unroll
    for (int j = 0; j < JN; ++j)
      bfr[j] =
          *(const bf16x8*)(cB + 4096 + (wn + j * 16 + mr) * 32 + (q ^ rkey) * 8);
#pragma unroll
    for (int i = 0; i < 4; ++i)
#pragma unroll
      for (int j = 0; j < JN; ++j)
        acc[i][j] = __builtin_amdgcn_mfma_f32_16x16x32_bf16(af[i], bfr[j],
                                                            acc[i][j], 0, 0, 0);
    if (k + 2 < nst)
      asm volatile("s_waitcnt vmcnt(%0)" ::"n"(LPS) : "memory");  // k+1 landed
    else
      asm volatile("s_waitcnt vmcnt(0)" ::: "memory");  // drain tail
    __builtin_amdgcn_s_barrier();
    __bf16* tp = cB; cB = nB; nB = fB; fB = tp;
  }
  // ---- epilogue: stage C in LDS, coalesced write-out ----
  if (OMODE == 1) {
    constexpr int PS = BN + 8;
    __bf16* Cs = Sm;  // full smem reuse (post-barrier)
#pragma unroll
    for (int j = 0; j < JN; ++j) {
      float bscol = BIASROW ? 0.f : bias[bn + wn + j * 16 + mr];
#pragma unroll
      for (int i = 0; i < 4; ++i) {
#pragma unroll
        for (int r = 0; r < 4; ++r) {
          float v = acc[i][j][r] +
                    (BIASROW ? bias[bm + wm + i * 16 + q * 4 + r] : bscol);
          if (RELU) v = fmaxf(v, 0.f);
          Cs[(wm + i * 16 + q * 4 + r) * PS + wn + j * 16 + mr] = (__bf16)v;
        }
      }
    }
    __syncthreads();
    constexpr int lpr = BN / 8;    // lanes per row (16B each)
    constexpr int rpi = 512 / BN;  // rows per wave-iteration
    const int rl = lane / lpr, cl = (lane % lpr) * 8;
#pragma unroll
    for (int it = 0; it < BN / 16; ++it) {
      int row = wid * 32 + it * rpi + rl;
      bf16x8 v = *(const bf16x8*)&Cs[row * PS + cl];
      *(bf16x8*)((__bf16*)Cout + (size_t)(bm + row) * ldc + bn + cl) = v;
    }
  } else {
    // OMODE==2: f32 staged once, dual coalesced output (f32 + bf16). BN=64.
    constexpr int PSF = BN + 4;
    float* Csf = (float*)Sm;
#pragma unroll
    for (int j = 0; j < JN; ++j) {
      float bscol = bias[bn + wn + j * 16 + mr];
#pragma unroll
      for (int i = 0; i < 4; ++i) {
#pragma unroll
        for (int r = 0; r < 4; ++r) {
          float v = acc[i][j][r] + bscol;
          if (RELU) v = fmaxf(v, 0.f);
          Csf[(wm + i * 16 + q * 4 + r) * PSF + wn + j * 16 + mr] = v;
        }
      }
    }
    __syncthreads();
    const int rl = lane >> 4, cl = (lane & 15) * 4;
#pragma unroll
    for (int it = 0; it < 8; ++it) {
      int row = wid * 32 + it * 4 + rl;
      f32x4 v = *(const f32x4*)&Csf[row * PSF + cl];
      size_t gidx = (size_t)(bm + row) * ldc + bn + cl;
      *(f32x4*)((float*)Cout + gidx) = v;
      bf16x4 vb = {(__bf16)v[0], (__bf16)v[1], (__bf16)v[2], (__bf16)v[3]};
      *(bf16x4*)(Cout2 + gidx) = vb;
    }
  }
}

// ---------------- fused ds + keys + vT GEMM (one launch, 3328 blocks) ----------------
__global__ __launch_bounds__(256) void gemm3_kernel(
    const __bf16* __restrict__ ki, const __bf16* __restrict__ ds_wt,
    const float* __restrict__ ds_b, float* __restrict__ att,
    __bf16* __restrict__ att_bf, const __bf16* __restrict__ kv_wt,
    const float* __restrict__ kvb, __bf16* __restrict__ kvs_k,
    __bf16* __restrict__ vT) {
  __shared__ __bf16 smem[24576];  // 3-buf staging 24576; epilogue <= 17408
  int bid = blockIdx.x;  // identity mapping (both swizzles measured worse)
  if (bid < 256) {
    // ds: att(+bf) = pred @ ds_w + b  [4096 x 512], K=256, A rows inside ki
    gemm_core<64, 2, false, true, false>(bid & 7, bid >> 3, ki, ds_wt, ds_b,
                                         att, att_bf, 256, kKP, 512, smem);
  } else if (bid < 1792) {
    // keys: [12288 x 2048]
    int b2 = bid - 256;
    gemm_core<128, 1, false, false, false>(b2 & 15, b2 >> 4, ki, kv_wt, kvb,
                                           kvs_k, nullptr, kKP, kKP, 2048,
                                           smem);
  } else {
    // values^T: [2048 x 12288] = Wv^T @ ki^T (bias per row)
    int b3 = bid - 1792;
    gemm_core<128, 1, false, false, true>(b3 % 96, b3 / 96,
                                          kv_wt + (size_t)2048 * kKP, ki,
                                          kvb + 2048, vT, nullptr, kKP, kKP,
                                          12288, smem);
  }
}

// ---------------- ff GEMMs (gemm_core wrappers) ----------------
template <bool RELU>
__global__ __launch_bounds__(256) void gemm_ff_kernel(
    const __bf16* __restrict__ A, const __bf16* __restrict__ Bt,
    const float* __restrict__ bias, __bf16* __restrict__ Cout) {
  __shared__ __bf16 smem[18432];  // 3-buf staging 18432; epilogue 9216
  gemm_core<64, 1, RELU, false, false>(blockIdx.x, blockIdx.y, A, Bt, bias,
                                       Cout, nullptr, 512, 512, 512, smem);
}

// ---------------- MFMA flash attention (S^T variant, reg-prefetched) --------
// 1-D grid of 512 blocks, XCD-pinned: id&7 == b&7 (measured neutral, kept).
__global__ __launch_bounds__(256) void attn_mfma_kernel(
    const __bf16* __restrict__ attbf, const __bf16* __restrict__ kvs_k,
    const __bf16* __restrict__ vT, __bf16* __restrict__ outbf, int l) {
  const int id = blockIdx.x;
  const int kk = id >> 3;
  const int b = ((kk >> 5) << 3) | (id & 7);
  const int qt = kk & 3;
  const int h = (kk >> 2) & 7;
  __shared__ __bf16 Ks[64 * 72];
  __shared__ __bf16 Vt[64 * 72];
  __shared__ __bf16 Ps[64 * 72];
  const int t = threadIdx.x;
  const int w = t >> 6, lane = t & 63;
  const int quad = lane >> 4, mr = lane & 15;
  bf16x8 aq[2];
  {
    const __bf16* qp = attbf + ((size_t)(b * kNV + qt * 64 + w * 16 + mr) * kHA +
                                h * kA + quad * 8);
    aq[0] = *(const bf16x8*)qp;
    aq[1] = *(const bf16x8*)(qp + 32);
  }
  f32x4 o[4] = {};
  float m_ = -1e30f, l_ = 0.f;
  const int cmax = kNH + qt * 64;
  const int pr = t >> 2, pc = t & 3;
  const __bf16* kbase = kvs_k + ((size_t)(b * kW + pr) * 2048 + l * 512 + h * kA);
  const __bf16* vbase = vT + (size_t)(l * 512 + h * kA + pr) * 12288 + b * kW;
  bf16x8 kc0, kc1, vc0, vc1;
  kc0 = *(const bf16x8*)(kbase + pc * 8);
  kc1 = *(const bf16x8*)(kbase + pc * 8 + 32);
  vc0 = *(const bf16x8*)(vbase + pc * 16);
  vc1 = *(const bf16x8*)(vbase + pc * 16 + 8);
  for (int c0 = 0; c0 <= cmax; c0 += 64) {
    __syncthreads();
    *(bf16x8*)&Ks[pr * 72 + pc * 8] = kc0;
    *(bf16x8*)&Ks[pr * 72 + pc * 8 + 32] = kc1;
    *(bf16x8*)&Vt[pr * 72 + pc * 16] = vc0;
    *(bf16x8*)&Vt[pr * 72 + pc * 16 + 8] = vc1;
    __syncthreads();
    if (c0 + 64 <= cmax) {
      const __bf16* kp = kbase + (size_t)(c0 + 64) * 2048;
      const __bf16* vp = vbase + c0 + 64;
      kc0 = *(const bf16x8*)(kp + pc * 8);
      kc1 = *(const bf16x8*)(kp + pc * 8 + 32);
      vc0 = *(const bf16x8*)(vp + pc * 16);
      vc1 = *(const bf16x8*)(vp + pc * 16 + 8);
    }
    // ---- S^T = K·Q^T ----
    f32x4 s[4];
#pragma unroll
    for (int j = 0; j < 4; ++j) {
      bf16x8 ak0 = *(const bf16x8*)&Ks[(j * 16 + mr) * 72 + quad * 8];
      bf16x8 ak1 = *(const bf16x8*)&Ks[(j * 16 + mr) * 72 + quad * 8 + 32];
      f32x4 z = {};
      z = __builtin_amdgcn_mfma_f32_16x16x32_bf16(ak0, aq[0], z, 0, 0, 0);
      z = __builtin_amdgcn_mfma_f32_16x16x32_bf16(ak1, aq[1], z, 0, 0, 0);
      s[j] = z;
    }
    const int lim = cmax - c0;
    float sv[16], mx = -1e30f;
#pragma unroll
    for (int j = 0; j < 4; ++j)
#pragma unroll
      for (int r = 0; r < 4; ++r) {
        int p = j * 16 + quad * 4 + r;
        float x = (p < lim + mr) ? s[j][r] * 0.125f : -1e30f;
        sv[j * 4 + r] = x;
        mx = fmaxf(mx, x);
      }
    mx = fmaxf(mx, __shfl_xor(mx, 16));
    mx = fmaxf(mx, __shfl_xor(mx, 32));
    float mnew = fmaxf(m_, mx);
    float corr = __expf(m_ - mnew);
    float rs = 0.f;
#pragma unroll
    for (int i = 0; i < 16; ++i) {
      sv[i] = __expf(sv[i] - mnew);
      rs += sv[i];
    }
    rs += __shfl_xor(rs, 16);
    rs += __shfl_xor(rs, 32);
    l_ = l_ * corr + rs;
    m_ = mnew;
#pragma unroll
    for (int j = 0; j < 4; ++j) {
      bf16x4 pk = {(__bf16)sv[j * 4 + 0], (__bf16)sv[j * 4 + 1],
                   (__bf16)sv[j * 4 + 2], (__bf16)sv[j * 4 + 3]};
      *(bf16x4*)&Ps[(w * 16 + mr) * 72 + j * 16 + quad * 4] = pk;
    }
#pragma unroll
    for (int r = 0; r < 4; ++r) {
      float cr = __shfl(corr, quad * 4 + r);
#pragma unroll
      for (int j = 0; j < 4; ++j) o[j][r] *= cr;
    }
    bf16x8 ap0 = *(const bf16x8*)&Ps[(w * 16 + mr) * 72 + quad * 8];
    bf16x8 ap1 = *(const bf16x8*)&Ps[(w * 16 + mr) * 72 + quad * 8 + 32];
#pragma unroll
    for (int j = 0; j < 4; ++j) {
      bf16x8 b0 = *(const bf16x8*)&Vt[(j * 16 + mr) * 72 + quad * 8];
      bf16x8 b1 = *(const bf16x8*)&Vt[(j * 16 + mr) * 72 + quad * 8 + 32];
      o[j] = __builtin_amdgcn_mfma_f32_16x16x32_bf16(ap0, b0, o[j], 0, 0, 0);
      o[j] = __builtin_amdgcn_mfma_f32_16x16x32_bf16(ap1, b1, o[j], 0, 0, 0);
    }
  }
  float invl = 1.f / l_;
#pragma unroll
  for (int r = 0; r < 4; ++r) {
    float ir = __shfl(invl, quad * 4 + r);
    int row = b * kNV + qt * 64 + w * 16 + quad * 4 + r;
#pragma unroll
    for (int j = 0; j < 4; ++j)
      outbf[(size_t)row * kHA + h * kA + j * 16 + mr] = (__bf16)(o[j][r] * ir);
  }
}

// ---------------- att = LN(att + add_bf); emits bf16 copy ----------------
__global__ __launch_bounds__(128) void add_ln_kernel(
    float* __restrict__ att, const __bf16* __restrict__ addbf,
    const float* __restrict__ g, const float* __restrict__ be,
    __bf16* __restrict__ attbf) {
  const int row = blockIdx.x;
  const int t = threadIdx.x;
  float4* ar = (float4*)(att + (size_t)row * kHA);
  bf16x4 dv = *(const bf16x4*)(addbf + (size_t)row * kHA + t * 4);
  float4 x = ar[t];
  x.x += (float)dv[0]; x.y += (float)dv[1];
  x.z += (float)dv[2]; x.w += (float)dv[3];
  float s = x.x + x.y + x.z + x.w;
  float sq = x.x * x.x + x.y * x.y + x.z * x.z + x.w * x.w;
  for (int o = 32; o; o >>= 1) {
    s += __shfl_xor(s, o);
    sq += __shfl_xor(sq, o);
  }
  __shared__ float red[4];
  if ((t & 63) == 0) { red[(t >> 6) * 2] = s; red[(t >> 6) * 2 + 1] = sq; }
  __syncthreads();
  float S = red[0] + red[2], Q = red[1] + red[3];
  float mean = S * (1.f / kHA);
  float inv = rsqrtf(Q * (1.f / kHA) - mean * mean + 1e-5f);
  float4 gv = ((const float4*)g)[t];
  float4 bv = ((const float4*)be)[t];
  float4 y;
  y.x = gv.x * (x.x - mean) * inv + bv.x;
  y.y = gv.y * (x.y - mean) * inv + bv.y;
  y.z = gv.z * (x.z - mean) * inv + bv.z;
  y.w = gv.w * (x.w - mean) * inv + bv.w;
  ar[t] = y;
  bf16x4 yb = {(__bf16)y.x, (__bf16)y.y, (__bf16)y.z, (__bf16)y.w};
  *(bf16x4*)(attbf + (size_t)row * kHA + t * 4) = yb;
}

// ---------------- fused de-projection + loss (atomic into out) ----------------
__global__ __launch_bounds__(256) void de_loss_kernel(
    const __bf16* __restrict__ attbf, const __bf16* __restrict__ de_wt,
    const float* __restrict__ de_b, const float* __restrict__ pred_u,
    float* __restrict__ out) {
  const int blk = blockIdx.x;
  const int t = threadIdx.x;
  const int w = t >> 6, lane = t & 63, quad = lane >> 4, mr = lane & 15;
  const int row0 = blk * 64 + w * 16;
  f32x4 acc[8] = {};
  const __bf16* Ap = attbf + (size_t)(row0 + mr) * kHA + quad * 8;
#pragma unroll 4
  for (int k0 = 0; k0 < 512; k0 += 32) {
    bf16x8 a = *(const bf16x8*)(Ap + k0);
#pragma unroll
    for (int j = 0; j < 8; ++j) {
      bf16x8 bb =
          *(const bf16x8*)(de_wt + (size_t)(j * 16 + mr) * 512 + k0 + quad * 8);
      acc[j] = __builtin_amdgcn_mfma_f32_16x16x32_bf16(a, bb, acc[j], 0, 0, 0);
    }
  }
  float dbv[8];
#pragma unroll
  for (int j = 0; j < 8; ++j) dbv[j] = de_b[j * 16 + mr];
  float lpacc = 0.f;
#pragma unroll
  for (int r = 0; r < 4; ++r) {
    int row = row0 + quad * 4 + r;
    int v = row & 255;
    float lg[8], mx = -1e30f;
#pragma unroll
    for (int j = 0; j < 8; ++j) {
      lg[j] = acc[j][r] + dbv[j];
      mx = fmaxf(mx, lg[j]);
    }
    mx = fmaxf(mx, __shfl_xor(mx, 1));
    mx = fmaxf(mx, __shfl_xor(mx, 2));
    mx = fmaxf(mx, __shfl_xor(mx, 4));
    mx = fmaxf(mx, __shfl_xor(mx, 8));
    float se = 0.f;
#pragma unroll
    for (int j = 0; j < 8; ++j) se += __expf(lg[j] - mx);
    se += __shfl_xor(se, 1);
    se += __shfl_xor(se, 2);
    se += __shfl_xor(se, 4);
    se += __shfl_xor(se, 8);
    float lse = mx + __logf(se);
    float u = pred_u[(row >> 8) * 256 + v];
    int tgt = (int)floorf(u * 128.f);
    tgt = max(0, min(127, tgt));
    float cand = (mr == (tgt & 15)) ? lg[tgt >> 4] : 0.f;
    cand += __shfl_xor(cand, 1);
    cand += __shfl_xor(cand, 2);
    cand += __shfl_xor(cand, 4);
    cand += __shfl_xor(cand, 8);
    float lp = (v >= 1) ? (4.8520302639196171f + cand - lse) : 0.f;  // ln(128)
    lpacc += lp;
  }
  lpacc += __shfl_xor(lpacc, 16);
  lpacc += __shfl_xor(lpacc, 32);
  __shared__ float red[4];
  if (lane == 0) red[w] = lpacc;
  __syncthreads();
  if (t == 0)
    atomicAdd(&out[blk >> 2], -(red[0] + red[1] + red[2] + red[3]));
}

extern "C" void kernel_launch(void* const* d_in, const int* in_sizes, int n_in,
                              void* d_out, int out_size, void* d_ws, size_t ws_size,
                              hipStream_t stream) {
  const float* hist   = (const float*)d_in[0];
  const float* hist_u = (const float*)d_in[1];
  const float* pred   = (const float*)d_in[2];
  const float* pred_u = (const float*)d_in[3];
  const float* ds_w   = (const float*)d_in[4];
  const float* ds_b   = (const float*)d_in[5];
  const float* key_w  = (const float*)d_in[6];
  const float* key_b  = (const float*)d_in[7];
  const float* val_w  = (const float*)d_in[8];
  const float* val_b  = (const float*)d_in[9];
  const float* ln1_g  = (const float*)d_in[10];
  const float* ln1_b  = (const float*)d_in[11];
  const float* ln2_g  = (const float*)d_in[12];
  const float* ln2_b  = (const float*)d_in[13];
  const float* ff_w1  = (const float*)d_in[14];
  const float* ff_b1  = (const float*)d_in[15];
  const float* ff_w2  = (const float*)d_in[16];
  const float* ff_b2  = (const float*)d_in[17];
  const float* ff_w3  = (const float*)d_in[18];
  const float* ff_b3  = (const float*)d_in[19];
  const float* de_w   = (const float*)d_in[20];
  const float* de_b   = (const float*)d_in[21];
  float* out = (float*)d_out;

  char* ws = (char*)d_ws;
  size_t off = 0;
  auto alloc = [&](size_t bytes) { char* p = ws + off; off += bytes; return p; };
  __bf16* ki_bf  = (__bf16*)alloc((size_t)kB * kW * kKP * 2);       // 7.1 MB
  __bf16* kv_wt  = (__bf16*)alloc((size_t)4096 * kKP * 2);          // 2.4 MB
  __bf16* ffw_t  = (__bf16*)alloc((size_t)12 * 512 * 512 * 2);      // 6.3 MB
  __bf16* ds_wt  = (__bf16*)alloc((size_t)512 * 256 * 2);
  __bf16* de_wt  = (__bf16*)alloc((size_t)128 * 512 * 2);
  float*  kvb    = (float*)alloc((size_t)4096 * 4);
  __bf16* kvs_k  = (__bf16*)alloc((size_t)kB * kW * 2048 * 2);      // 50.3 MB
  __bf16* vT     = (__bf16*)alloc((size_t)2048 * 12288 * 2);        // 50.3 MB
  float*  att    = (float*)alloc((size_t)kRows * kHA * 4);          // 8.4 MB
  __bf16* att_bf = (__bf16*)alloc((size_t)kRows * kHA * 2);
  __bf16* tmp_bf = (__bf16*)alloc((size_t)kRows * kHA * 2);
  __bf16* ff1_bf = (__bf16*)alloc((size_t)kRows * kM * 2);
  __bf16* ff2_bf = (__bf16*)alloc((size_t)kRows * kM * 2);

  prep_kernel<<<(kPT + 255) / 256, 256, 0, stream>>>(
      hist, hist_u, pred, pred_u, key_w, val_w, ff_w1, ff_w2, ff_w3, ds_w, de_w,
      key_b, val_b, ki_bf, kv_wt, ffw_t, ds_wt, de_wt, kvb, out);

  // ds + keys + vT in one launch
  gemm3_kernel<<<3328, 256, 0, stream>>>(ki_bf, ds_wt, ds_b, att, att_bf, kv_wt,
                                         kvb, kvs_k, vT);

  for (int l = 0; l < kL; ++l) {
    attn_mfma_kernel<<<512, 256, 0, stream>>>(att_bf, kvs_k, vT, tmp_bf, l);
    add_ln_kernel<<<kRows, 128, 0, stream>>>(att, tmp_bf, ln1_g + l * kHA,
                                             ln1_b + l * kHA, att_bf);
    gemm_ff_kernel<true><<<dim3(kM / 64, kRows / 128), 256, 0, stream>>>(
        att_bf, ffw_t + (size_t)(l * 3) * 262144, ff_b1 + l * kM, ff1_bf);
    gemm_ff_kernel<true><<<dim3(kM / 64, kRows / 128), 256, 0, stream>>>(
        ff1_bf, ffw_t + (size_t)(l * 3 + 1) * 262144, ff_b2 + l * kM, ff2_bf);
    gemm_ff_kernel<false><<<dim3(kHA / 64, kRows / 128), 256, 0, stream>>>(
        ff2_bf, ffw_t + (size_t)(l * 3 + 2) * 262144, ff_b3 + l * kHA, tmp_bf);
    add_ln_kernel<<<kRows, 128, 0, stream>>>(att, tmp_bf, ln2_g + l * kHA,
                                             ln2_b + l * kHA, att_bf);
  }
  de_loss_kernel<<<64, 256, 0, stream>>>(att_bf, de_wt, de_b, pred_u, out);
}

// Round 8
// 436.253 us; speedup vs baseline: 1.1375x; 1.0148x over previous
//
#include <hip/hip_runtime.h>

// Problem constants (AttentionalCopula)
constexpr int kB = 16, kD = 256, kNH = 512, kNV = 256, kW = 768;
constexpr int kL = 4, kH = 8, kA = 64, kHA = 512, kM = 512, kR = 128;
constexpr int kKP = 288;  // K=257 zero-padded to multiple of 32
constexpr int kRows = kB * kNV;  // 4096

typedef __bf16 bf16x8 __attribute__((ext_vector_type(8)));
typedef __bf16 bf16x4 __attribute__((ext_vector_type(4)));
typedef float f32x4 __attribute__((ext_vector_type(4)));

__device__ inline void load_lds16(const __bf16* g, __bf16* l) {
  __builtin_amdgcn_global_load_lds(
      (const __attribute__((address_space(1))) void*)g,
      (__attribute__((address_space(3))) void*)l, 16, 0, 0);
}

// ---------------- merged prep kernel (1 launch) ----------------
constexpr int kP1 = kB * kW * kKP;        // ki
constexpr int kP2 = 4096 * kKP;           // kv weights
constexpr int kP3 = 12 * 512 * 512;       // ff weights
constexpr int kP4 = 200704;               // ds_wt, de_wt, kvb
constexpr int kP5 = 16;                   // zero d_out
constexpr int kPT = kP1 + kP2 + kP3 + kP4 + kP5;

__global__ void prep_kernel(const float* __restrict__ hist,
                            const float* __restrict__ hist_u,
                            const float* __restrict__ pred,
                            const float* __restrict__ pred_u,
                            const float* __restrict__ kw,
                            const float* __restrict__ vw,
                            const float* __restrict__ w1,
                            const float* __restrict__ w2,
                            const float* __restrict__ w3,
                            const float* __restrict__ ds_w,
                            const float* __restrict__ de_w,
                            const float* __restrict__ key_b,
                            const float* __restrict__ val_b,
                            __bf16* __restrict__ ki,
                            __bf16* __restrict__ kvwt,
                            __bf16* __restrict__ ffwt,
                            __bf16* __restrict__ ds_wt,
                            __bf16* __restrict__ de_wt,
                            float* __restrict__ kvb,
                            float* __restrict__ outz) {
  int i = blockIdx.x * 256 + threadIdx.x;
  if (i < kP1) {
    int d = i % kKP;
    int bw = i / kKP;
    int w = bw % kW;
    int b = bw / kW;
    float v = 0.f;
    if (d < 257) {
      if (w < kNH)
        v = (d < kD) ? hist[((size_t)b * kNH + w) * kD + d] : hist_u[b * kNH + w];
      else {
        int p = w - kNH;
        v = (d < kD) ? pred[((size_t)b * kNV + p) * kD + d] : pred_u[b * kNV + p];
      }
    }
    ki[i] = (__bf16)v;
  } else if (i < kP1 + kP2) {
    int j = i - kP1;
    int d = j % kKP;
    int c = j / kKP;
    float v = 0.f;
    if (d < 257) {
      bool isv = c >= 2048;
      int cc = isv ? c - 2048 : c;
      int l = cc >> 9, rest = cc & 511;
      int h = rest >> 6, a = rest & 63;
      size_t src = (((size_t)l * kH + h) * 257 + d) * kA + a;
      v = isv ? vw[src] : kw[src];
    }
    kvwt[j] = (__bf16)v;
  } else if (i < kP1 + kP2 + kP3) {
    int j = i - kP1 - kP2;
    int k = j & 511;
    int n = (j >> 9) & 511;
    int mat = j >> 18;
    int l = mat / 3, which = mat % 3;
    const float* src = which == 0 ? w1 : which == 1 ? w2 : w3;
    ffwt[j] = (__bf16)src[((size_t)l * 512 + k) * 512 + n];
  } else if (i < kP1 + kP2 + kP3 + kP4) {
    int j = i - kP1 - kP2 - kP3;
    if (j < 131072) {
      int n = j >> 8, k = j & 255;
      ds_wt[j] = (__bf16)ds_w[k * 512 + n];
    } else if (j < 196608) {
      int jj = j - 131072;
      int n = jj >> 9, k = jj & 511;
      de_wt[jj] = (__bf16)de_w[k * 128 + n];
    } else {
      int c = j - 196608;  // 0..4095
      bool isv = c >= 2048;
      int cc = isv ? c - 2048 : c;
      int l = cc >> 9, rest = cc & 511;
      kvb[c] = isv ? val_b[l * 512 + rest] : key_b[l * 512 + rest];
    }
  } else if (i < kPT) {
    outz[i - kP1 - kP2 - kP3 - kP4] = 0.f;
  }
}

// ---- generic bf16 MFMA GEMM core (DEPTH-buffer counted-vmcnt pipeline) ------
// T4 pattern: distance-(DEPTH-1) prefetch, raw s_barrier + counted s_waitcnt
// so prefetch global_load_lds stay in flight across barriers (never drain
// vmcnt to 0 mid-loop). DEPTH=3 for gemm3 (compute/step large), DEPTH=4 for
// ff (8 MFMA/wave/step < L2 latency -> needs 2 stages of cover at 1 blk/CU).
// OMODE: 1=bf16 out, 2=f32+bf16 out. XOR-swizzled staging, coalesced epilogue.
// KIMAP: A rows remap r -> (r>>8)*768 + 512 + (r&255). BIASROW: bias by row.
// Sm elems needed: DEPTH*SSTEP vs epilogue tile:
//   BN=128 OMODE1 D3: max(24576, 17408) = 24576
//   BN=64  OMODE2 D3: max(18432, 17408) = 18432
//   BN=64  OMODE1 D4: max(24576, 9216)  = 24576
template <int BN, int OMODE, bool RELU, bool KIMAP, bool BIASROW, int DEPTH>
__device__ __forceinline__ void gemm_core(
    int bxv, int byv, const __bf16* __restrict__ A,
    const __bf16* __restrict__ Bt, const float* __restrict__ bias,
    void* __restrict__ Cout, __bf16* __restrict__ Cout2, int K, int lda,
    int ldc, __bf16* Sm) {
  constexpr int JN = BN / 32;
  constexpr int BROWS = BN / 4;
  constexpr int SSTEP = (128 + BN) * 32;       // one stage buffer, bf16 elems
  constexpr int LPS = (BN == 128) ? 4 : 3;     // global_load_lds per wave/stage
  constexpr int AH = DEPTH - 1;                // stages prefetched ahead
  const int t = threadIdx.x;
  const int wid = t >> 6;
  const int lane = t & 63;
  const int bm = byv * 128;
  const int bn = bxv * BN;
  const int wm = (wid >> 1) * 64;
  const int wn = (wid & 1) * (BN / 2);
  const int sr = lane >> 2, sc = lane & 3;
  const int skey = (sr >> 1) & 3;
  const int abase = KIMAP ? ((bm >> 8) * 768 + 512 + (bm & 255)) : bm;
  const __bf16* Ag = A + (size_t)(abase + wid * 32 + sr) * lda + (sc ^ skey) * 8;
  const __bf16* Bg = Bt + (size_t)(bn + wid * BROWS + sr) * K + (sc ^ skey) * 8;

  auto stage = [&](int k0, __bf16* buf) {
    __bf16* As = buf;
    __bf16* Bs = buf + 4096;
    load_lds16(Ag + k0, As + (wid * 32) * 32);
    load_lds16(Ag + (size_t)16 * lda + k0, As + (wid * 32 + 16) * 32);
    load_lds16(Bg + k0, Bs + (wid * BROWS) * 32);
    if (BN == 128)
      load_lds16(Bg + (size_t)16 * K + k0, Bs + (wid * BROWS + 16) * 32);
  };

  f32x4 acc[4][JN] = {};
  const int q = lane >> 4, mr = lane & 15;
  const int rkey = (mr >> 1) & 3;
  const int nst = K >> 5;  // assumed >= DEPTH-1 (min here: 8)
  __bf16* b0 = Sm;               // current compute
  __bf16* b1 = Sm + SSTEP;       // next (landed at barrier)
  __bf16* b2 = Sm + 2 * SSTEP;   // in flight
  __bf16* b3 = (DEPTH == 4) ? Sm + 3 * SSTEP : nullptr;  // in flight (D4)
  stage(0, b0);
  stage(32, b1);
  if constexpr (DEPTH == 4) stage(64, b2);
  asm volatile("s_waitcnt vmcnt(%0)" ::"n"((AH - 1) * LPS) : "memory");
  __builtin_amdgcn_s_barrier();
  for (int k = 0; k < nst; ++k) {
    if (k + AH < nst) {
      if constexpr (DEPTH == 4) stage((k + AH) << 5, b3);
      else stage((k + AH) << 5, b2);
    }
    bf16x8 af[4], bfr[JN];
#pragma unroll
    for (int i = 0; i < 4; ++i)
      af[i] = *(const bf16x8*)(b0 + (wm + i * 16 + mr) * 32 + (q ^ rkey) * 8);
#pragma unroll
    for (int j = 0; j < JN; ++j)
      bfr[j] =
          *(const bf16x8*)(b0 + 4096 + (wn + j * 16 + mr) * 32 + (q ^ rkey) * 8);
#pragma unroll
    for (int i = 0; i < 4; ++i)
#pragma unroll
      for (int j = 0; j < JN; ++j)
        acc[i][j] = __builtin_amdgcn_mfma_f32_16x16x32_bf16(af[i], bfr[j],
                                                            acc[i][j], 0, 0, 0);
    // counted wait: need stage k+1 landed; keep younger stages in flight.
    if (k + AH + 1 <= nst)
      asm volatile("s_waitcnt vmcnt(%0)" ::"n"((AH - 1) * LPS) : "memory");
    else if (DEPTH == 4 && k + AH == nst + 1)
      asm volatile("s_waitcnt vmcnt(%0)" ::"n"(LPS) : "memory");
    else
      asm volatile("s_waitcnt vmcnt(0)" ::: "memory");
    __builtin_amdgcn_s_barrier();
    if constexpr (DEPTH == 4) {
      __bf16* tp = b0; b0 = b1; b1 = b2; b2 = b3; b3 = tp;
    } else {
      __bf16* tp = b0; b0 = b1; b1 = b2; b2 = tp;
    }
  }
  // ---- epilogue: stage C in LDS, coalesced write-out ----
  if (OMODE == 1) {
    constexpr int PS = BN + 8;
    __bf16* Cs = Sm;  // full smem reuse (post-barrier)
#pragma unroll
    for (int j = 0; j < JN; ++j) {
      float bscol = BIASROW ? 0.f : bias[bn + wn + j * 16 + mr];
#pragma unroll
      for (int i = 0; i < 4; ++i) {
#pragma unroll
        for (int r = 0; r < 4; ++r) {
          float v = acc[i][j][r] +
                    (BIASROW ? bias[bm + wm + i * 16 + q * 4 + r] : bscol);
          if (RELU) v = fmaxf(v, 0.f);
          Cs[(wm + i * 16 + q * 4 + r) * PS + wn + j * 16 + mr] = (__bf16)v;
        }
      }
    }
    __syncthreads();
    constexpr int lpr = BN / 8;    // lanes per row (16B each)
    constexpr int rpi = 512 / BN;  // rows per wave-iteration
    const int rl = lane / lpr, cl = (lane % lpr) * 8;
#pragma unroll
    for (int it = 0; it < BN / 16; ++it) {
      int row = wid * 32 + it * rpi + rl;
      bf16x8 v = *(const bf16x8*)&Cs[row * PS + cl];
      *(bf16x8*)((__bf16*)Cout + (size_t)(bm + row) * ldc + bn + cl) = v;
    }
  } else {
    // OMODE==2: f32 staged once, dual coalesced output (f32 + bf16). BN=64.
    constexpr int PSF = BN + 4;
    float* Csf = (float*)Sm;
#pragma unroll
    for (int j = 0; j < JN; ++j) {
      float bscol = bias[bn + wn + j * 16 + mr];
#pragma unroll
      for (int i = 0; i < 4; ++i) {
#pragma unroll
        for (int r = 0; r < 4; ++r) {
          float v = acc[i][j][r] + bscol;
          if (RELU) v = fmaxf(v, 0.f);
          Csf[(wm + i * 16 + q * 4 + r) * PSF + wn + j * 16 + mr] = v;
        }
      }
    }
    __syncthreads();
    const int rl = lane >> 4, cl = (lane & 15) * 4;
#pragma unroll
    for (int it = 0; it < 8; ++it) {
      int row = wid * 32 + it * 4 + rl;
      f32x4 v = *(const f32x4*)&Csf[row * PSF + cl];
      size_t gidx = (size_t)(bm + row) * ldc + bn + cl;
      *(f32x4*)((float*)Cout + gidx) = v;
      bf16x4 vb = {(__bf16)v[0], (__bf16)v[1], (__bf16)v[2], (__bf16)v[3]};
      *(bf16x4*)(Cout2 + gidx) = vb;
    }
  }
}

// ---------------- fused ds + keys + vT GEMM (one launch, 3328 blocks) ----------------
__global__ __launch_bounds__(256) void gemm3_kernel(
    const __bf16* __restrict__ ki, const __bf16* __restrict__ ds_wt,
    const float* __restrict__ ds_b, float* __restrict__ att,
    __bf16* __restrict__ att_bf, const __bf16* __restrict__ kv_wt,
    const float* __restrict__ kvb, __bf16* __restrict__ kvs_k,
    __bf16* __restrict__ vT) {
  __shared__ __bf16 smem[24576];  // 3-buf staging 24576; epilogue <= 17408
  int bid = blockIdx.x;  // identity mapping (both swizzles measured worse)
  if (bid < 256) {
    // ds: att(+bf) = pred @ ds_w + b  [4096 x 512], K=256, A rows inside ki
    gemm_core<64, 2, false, true, false, 3>(bid & 7, bid >> 3, ki, ds_wt, ds_b,
                                            att, att_bf, 256, kKP, 512, smem);
  } else if (bid < 1792) {
    // keys: [12288 x 2048]
    int b2 = bid - 256;
    gemm_core<128, 1, false, false, false, 3>(b2 & 15, b2 >> 4, ki, kv_wt, kvb,
                                              kvs_k, nullptr, kKP, kKP, 2048,
                                              smem);
  } else {
    // values^T: [2048 x 12288] = Wv^T @ ki^T (bias per row)
    int b3 = bid - 1792;
    gemm_core<128, 1, false, false, true, 3>(b3 % 96, b3 / 96,
                                             kv_wt + (size_t)2048 * kKP, ki,
                                             kvb + 2048, vT, nullptr, kKP, kKP,
                                             12288, smem);
  }
}

// ---------------- ff GEMMs (gemm_core wrappers, 4-deep pipeline) ------------
template <bool RELU>
__global__ __launch_bounds__(256) void gemm_ff_kernel(
    const __bf16* __restrict__ A, const __bf16* __restrict__ Bt,
    const float* __restrict__ bias, __bf16* __restrict__ Cout) {
  __shared__ __bf16 smem[24576];  // 4-buf staging 24576; epilogue 9216
  gemm_core<64, 1, RELU, false, false, 4>(blockIdx.x, blockIdx.y, A, Bt, bias,
                                          Cout, nullptr, 512, 512, 512, smem);
}

// ---------------- MFMA flash attention (S^T variant, reg-prefetched) --------
// 1-D grid of 512 blocks, XCD-pinned: id&7 == b&7 (measured neutral, kept).
__global__ __launch_bounds__(256) void attn_mfma_kernel(
    const __bf16* __restrict__ attbf, const __bf16* __restrict__ kvs_k,
    const __bf16* __restrict__ vT, __bf16* __restrict__ outbf, int l) {
  const int id = blockIdx.x;
  const int kk = id >> 3;
  const int b = ((kk >> 5) << 3) | (id & 7);
  const int qt = kk & 3;
  const int h = (kk >> 2) & 7;
  __shared__ __bf16 Ks[64 * 72];
  __shared__ __bf16 Vt[64 * 72];
  __shared__ __bf16 Ps[64 * 72];
  const int t = threadIdx.x;
  const int w = t >> 6, lane = t & 63;
  const int quad = lane >> 4, mr = lane & 15;
  bf16x8 aq[2];
  {
    const __bf16* qp = attbf + ((size_t)(b * kNV + qt * 64 + w * 16 + mr) * kHA +
                                h * kA + quad * 8);
    aq[0] = *(const bf16x8*)qp;
    aq[1] = *(const bf16x8*)(qp + 32);
  }
  f32x4 o[4] = {};
  float m_ = -1e30f, l_ = 0.f;
  const int cmax = kNH + qt * 64;
  const int pr = t >> 2, pc = t & 3;
  const __bf16* kbase = kvs_k + ((size_t)(b * kW + pr) * 2048 + l * 512 + h * kA);
  const __bf16* vbase = vT + (size_t)(l * 512 + h * kA + pr) * 12288 + b * kW;
  bf16x8 kc0, kc1, vc0, vc1;
  kc0 = *(const bf16x8*)(kbase + pc * 8);
  kc1 = *(const bf16x8*)(kbase + pc * 8 + 32);
  vc0 = *(const bf16x8*)(vbase + pc * 16);
  vc1 = *(const bf16x8*)(vbase + pc * 16 + 8);
  for (int c0 = 0; c0 <= cmax; c0 += 64) {
    __syncthreads();
    *(bf16x8*)&Ks[pr * 72 + pc * 8] = kc0;
    *(bf16x8*)&Ks[pr * 72 + pc * 8 + 32] = kc1;
    *(bf16x8*)&Vt[pr * 72 + pc * 16] = vc0;
    *(bf16x8*)&Vt[pr * 72 + pc * 16 + 8] = vc1;
    __syncthreads();
    if (c0 + 64 <= cmax) {
      const __bf16* kp = kbase + (size_t)(c0 + 64) * 2048;
      const __bf16* vp = vbase + c0 + 64;
      kc0 = *(const bf16x8*)(kp + pc * 8);
      kc1 = *(const bf16x8*)(kp + pc * 8 + 32);
      vc0 = *(const bf16x8*)(vp + pc * 16);
      vc1 = *(const bf16x8*)(vp + pc * 16 + 8);
    }
    // ---- S^T = K·Q^T ----
    f32x4 s[4];
#pragma unroll
    for (int j = 0; j < 4; ++j) {
      bf16x8 ak0 = *(const bf16x8*)&Ks[(j * 16 + mr) * 72 + quad * 8];
      bf16x8 ak1 = *(const bf16x8*)&Ks[(j * 16 + mr) * 72 + quad * 8 + 32];
      f32x4 z = {};
      z = __builtin_amdgcn_mfma_f32_16x16x32_bf16(ak0, aq[0], z, 0, 0, 0);
      z = __builtin_amdgcn_mfma_f32_16x16x32_bf16(ak1, aq[1], z, 0, 0, 0);
      s[j] = z;
    }
    const int lim = cmax - c0;
    float sv[16], mx = -1e30f;
#pragma unroll
    for (int j = 0; j < 4; ++j)
#pragma unroll
      for (int r = 0; r < 4; ++r) {
        int p = j * 16 + quad * 4 + r;
        float x = (p < lim + mr) ? s[j][r] * 0.125f : -1e30f;
        sv[j * 4 + r] = x;
        mx = fmaxf(mx, x);
      }
    mx = fmaxf(mx, __shfl_xor(mx, 16));
    mx = fmaxf(mx, __shfl_xor(mx, 32));
    float mnew = fmaxf(m_, mx);
    float corr = __expf(m_ - mnew);
    float rs = 0.f;
#pragma unroll
    for (int i = 0; i < 16; ++i) {
      sv[i] = __expf(sv[i] - mnew);
      rs += sv[i];
    }
    rs += __shfl_xor(rs, 16);
    rs += __shfl_xor(rs, 32);
    l_ = l_ * corr + rs;
    m_ = mnew;
#pragma unroll
    for (int j = 0; j < 4; ++j) {
      bf16x4 pk = {(__bf16)sv[j * 4 + 0], (__bf16)sv[j * 4 + 1],
                   (__bf16)sv[j * 4 + 2], (__bf16)sv[j * 4 + 3]};
      *(bf16x4*)&Ps[(w * 16 + mr) * 72 + j * 16 + quad * 4] = pk;
    }
#pragma unroll
    for (int r = 0; r < 4; ++r) {
      float cr = __shfl(corr, quad * 4 + r);
#pragma unroll
      for (int j = 0; j < 4; ++j) o[j][r] *= cr;
    }
    bf16x8 ap0 = *(const bf16x8*)&Ps[(w * 16 + mr) * 72 + quad * 8];
    bf16x8 ap1 = *(const bf16x8*)&Ps[(w * 16 + mr) * 72 + quad * 8 + 32];
#pragma unroll
    for (int j = 0; j < 4; ++j) {
      bf16x8 b0 = *(const bf16x8*)&Vt[(j * 16 + mr) * 72 + quad * 8];
      bf16x8 b1 = *(const bf16x8*)&Vt[(j * 16 + mr) * 72 + quad * 8 + 32];
      o[j] = __builtin_amdgcn_mfma_f32_16x16x32_bf16(ap0, b0, o[j], 0, 0, 0);
      o[j] = __builtin_amdgcn_mfma_f32_16x16x32_bf16(ap1, b1, o[j], 0, 0, 0);
    }
  }
  float invl = 1.f / l_;
#pragma unroll
  for (int r = 0; r < 4; ++r) {
    float ir = __shfl(invl, quad * 4 + r);
    int row = b * kNV + qt * 64 + w * 16 + quad * 4 + r;
#pragma unroll
    for (int j = 0; j < 4; ++j)
      outbf[(size_t)row * kHA + h * kA + j * 16 + mr] = (__bf16)(o[j][r] * ir);
  }
}

// --------- att = LN(att + add_bf); wave-per-row, no LDS, no barrier ---------
__global__ __launch_bounds__(256) void add_ln_kernel(
    float* __restrict__ att, const __bf16* __restrict__ addbf,
    const float* __restrict__ g, const float* __restrict__ be,
    __bf16* __restrict__ attbf) {
  const int w = threadIdx.x >> 6, lane = threadIdx.x & 63;
  const int row = blockIdx.x * 4 + w;
  const int c0 = lane * 8;
  const size_t base = (size_t)row * kHA + c0;
  float4 a0 = *(const float4*)(att + base);
  float4 a1 = *(const float4*)(att + base + 4);
  bf16x8 dv = *(const bf16x8*)(addbf + base);
  float x[8] = {a0.x + (float)dv[0], a0.y + (float)dv[1], a0.z + (float)dv[2],
                a0.w + (float)dv[3], a1.x + (float)dv[4], a1.y + (float)dv[5],
                a1.z + (float)dv[6], a1.w + (float)dv[7]};
  float s = 0.f, q = 0.f;
#pragma unroll
  for (int j = 0; j < 8; ++j) { s += x[j]; q += x[j] * x[j]; }
#pragma unroll
  for (int o = 1; o < 64; o <<= 1) {
    s += __shfl_xor(s, o);
    q += __shfl_xor(q, o);
  }
  const float mean = s * (1.f / kHA);
  const float inv = rsqrtf(q * (1.f / kHA) - mean * mean + 1e-5f);
  float4 g0 = *(const float4*)(g + c0);
  float4 g1 = *(const float4*)(g + c0 + 4);
  float4 e0 = *(const float4*)(be + c0);
  float4 e1 = *(const float4*)(be + c0 + 4);
  float y[8];
  y[0] = g0.x * (x[0] - mean) * inv + e0.x;
  y[1] = g0.y * (x[1] - mean) * inv + e0.y;
  y[2] = g0.z * (x[2] - mean) * inv + e0.z;
  y[3] = g0.w * (x[3] - mean) * inv + e0.w;
  y[4] = g1.x * (x[4] - mean) * inv + e1.x;
  y[5] = g1.y * (x[5] - mean) * inv + e1.y;
  y[6] = g1.z * (x[6] - mean) * inv + e1.z;
  y[7] = g1.w * (x[7] - mean) * inv + e1.w;
  *(float4*)(att + base) = (float4){y[0], y[1], y[2], y[3]};
  *(float4*)(att + base + 4) = (float4){y[4], y[5], y[6], y[7]};
  bf16x8 yb = {(__bf16)y[0], (__bf16)y[1], (__bf16)y[2], (__bf16)y[3],
               (__bf16)y[4], (__bf16)y[5], (__bf16)y[6], (__bf16)y[7]};
  *(bf16x8*)(attbf + base) = yb;
}

// ---------------- fused de-projection + loss (atomic into out) ----------------
__global__ __launch_bounds__(256) void de_loss_kernel(
    const __bf16* __restrict__ attbf, const __bf16* __restrict__ de_wt,
    const float* __restrict__ de_b, const float* __restrict__ pred_u,
    float* __restrict__ out) {
  const int blk = blockIdx.x;
  const int t = threadIdx.x;
  const int w = t >> 6, lane = t & 63, quad = lane >> 4, mr = lane & 15;
  const int row0 = blk * 64 + w * 16;
  f32x4 acc[8] = {};
  const __bf16* Ap = attbf + (size_t)(row0 + mr) * kHA + quad * 8;
#pragma unroll 4
  for (int k0 = 0; k0 < 512; k0 += 32) {
    bf16x8 a = *(const bf16x8*)(Ap + k0);
#pragma unroll
    for (int j = 0; j < 8; ++j) {
      bf16x8 bb =
          *(const bf16x8*)(de_wt + (size_t)(j * 16 + mr) * 512 + k0 + quad * 8);
      acc[j] = __builtin_amdgcn_mfma_f32_16x16x32_bf16(a, bb, acc[j], 0, 0, 0);
    }
  }
  float dbv[8];
#pragma unroll
  for (int j = 0; j < 8; ++j) dbv[j] = de_b[j * 16 + mr];
  float lpacc = 0.f;
#pragma unroll
  for (int r = 0; r < 4; ++r) {
    int row = row0 + quad * 4 + r;
    int v = row & 255;
    float lg[8], mx = -1e30f;
#pragma unroll
    for (int j = 0; j < 8; ++j) {
      lg[j] = acc[j][r] + dbv[j];
      mx = fmaxf(mx, lg[j]);
    }
    mx = fmaxf(mx, __shfl_xor(mx, 1));
    mx = fmaxf(mx, __shfl_xor(mx, 2));
    mx = fmaxf(mx, __shfl_xor(mx, 4));
    mx = fmaxf(mx, __shfl_xor(mx, 8));
    float se = 0.f;
#pragma unroll
    for (int j = 0; j < 8; ++j) se += __expf(lg[j] - mx);
    se += __shfl_xor(se, 1);
    se += __shfl_xor(se, 2);
    se += __shfl_xor(se, 4);
    se += __shfl_xor(se, 8);
    float lse = mx + __logf(se);
    float u = pred_u[(row >> 8) * 256 + v];
    int tgt = (int)floorf(u * 128.f);
    tgt = max(0, min(127, tgt));
    float cand = (mr == (tgt & 15)) ? lg[tgt >> 4] : 0.f;
    cand += __shfl_xor(cand, 1);
    cand += __shfl_xor(cand, 2);
    cand += __shfl_xor(cand, 4);
    cand += __shfl_xor(cand, 8);
    float lp = (v >= 1) ? (4.8520302639196171f + cand - lse) : 0.f;  // ln(128)
    lpacc += lp;
  }
  lpacc += __shfl_xor(lpacc, 16);
  lpacc += __shfl_xor(lpacc, 32);
  __shared__ float red[4];
  if (lane == 0) red[w] = lpacc;
  __syncthreads();
  if (t == 0)
    atomicAdd(&out[blk >> 2], -(red[0] + red[1] + red[2] + red[3]));
}

extern "C" void kernel_launch(void* const* d_in, const int* in_sizes, int n_in,
                              void* d_out, int out_size, void* d_ws, size_t ws_size,
                              hipStream_t stream) {
  const float* hist   = (const float*)d_in[0];
  const float* hist_u = (const float*)d_in[1];
  const float* pred   = (const float*)d_in[2];
  const float* pred_u = (const float*)d_in[3];
  const float* ds_w   = (const float*)d_in[4];
  const float* ds_b   = (const float*)d_in[5];
  const float* key_w  = (const float*)d_in[6];
  const float* key_b  = (const float*)d_in[7];
  const float* val_w  = (const float*)d_in[8];
  const float* val_b  = (const float*)d_in[9];
  const float* ln1_g  = (const float*)d_in[10];
  const float* ln1_b  = (const float*)d_in[11];
  const float* ln2_g  = (const float*)d_in[12];
  const float* ln2_b  = (const float*)d_in[13];
  const float* ff_w1  = (const float*)d_in[14];
  const float* ff_b1  = (const float*)d_in[15];
  const float* ff_w2  = (const float*)d_in[16];
  const float* ff_b2  = (const float*)d_in[17];
  const float* ff_w3  = (const float*)d_in[18];
  const float* ff_b3  = (const float*)d_in[19];
  const float* de_w   = (const float*)d_in[20];
  const float* de_b   = (const float*)d_in[21];
  float* out = (float*)d_out;

  char* ws = (char*)d_ws;
  size_t off = 0;
  auto alloc = [&](size_t bytes) { char* p = ws + off; off += bytes; return p; };
  __bf16* ki_bf  = (__bf16*)alloc((size_t)kB * kW * kKP * 2);       // 7.1 MB
  __bf16* kv_wt  = (__bf16*)alloc((size_t)4096 * kKP * 2);          // 2.4 MB
  __bf16* ffw_t  = (__bf16*)alloc((size_t)12 * 512 * 512 * 2);      // 6.3 MB
  __bf16* ds_wt  = (__bf16*)alloc((size_t)512 * 256 * 2);
  __bf16* de_wt  = (__bf16*)alloc((size_t)128 * 512 * 2);
  float*  kvb    = (float*)alloc((size_t)4096 * 4);
  __bf16* kvs_k  = (__bf16*)alloc((size_t)kB * kW * 2048 * 2);      // 50.3 MB
  __bf16* vT     = (__bf16*)alloc((size_t)2048 * 12288 * 2);        // 50.3 MB
  float*  att    = (float*)alloc((size_t)kRows * kHA * 4);          // 8.4 MB
  __bf16* att_bf = (__bf16*)alloc((size_t)kRows * kHA * 2);
  __bf16* tmp_bf = (__bf16*)alloc((size_t)kRows * kHA * 2);
  __bf16* ff1_bf = (__bf16*)alloc((size_t)kRows * kM * 2);
  __bf16* ff2_bf = (__bf16*)alloc((size_t)kRows * kM * 2);

  prep_kernel<<<(kPT + 255) / 256, 256, 0, stream>>>(
      hist, hist_u, pred, pred_u, key_w, val_w, ff_w1, ff_w2, ff_w3, ds_w, de_w,
      key_b, val_b, ki_bf, kv_wt, ffw_t, ds_wt, de_wt, kvb, out);

  // ds + keys + vT in one launch
  gemm3_kernel<<<3328, 256, 0, stream>>>(ki_bf, ds_wt, ds_b, att, att_bf, kv_wt,
                                         kvb, kvs_k, vT);

  for (int l = 0; l < kL; ++l) {
    attn_mfma_kernel<<<512, 256, 0, stream>>>(att_bf, kvs_k, vT, tmp_bf, l);
    add_ln_kernel<<<kRows / 4, 256, 0, stream>>>(att, tmp_bf, ln1_g + l * kHA,
                                                 ln1_b + l * kHA, att_bf);
    gemm_ff_kernel<true><<<dim3(kM / 64, kRows / 128), 256, 0, stream>>>(
        att_bf, ffw_t + (size_t)(l * 3) * 262144, ff_b1 + l * kM, ff1_bf);
    gemm_ff_kernel<true><<<dim3(kM / 64, kRows / 128), 256, 0, stream>>>(
        ff1_bf, ffw_t + (size_t)(l * 3 + 1) * 262144, ff_b2 + l * kM, ff2_bf);
    gemm_ff_kernel<false><<<dim3(kHA / 64, kRows / 128), 256, 0, stream>>>(
        ff2_bf, ffw_t + (size_t)(l * 3 + 2) * 262144, ff_b3 + l * kHA, tmp_bf);
    add_ln_kernel<<<kRows / 4, 256, 0, stream>>>(att, tmp_bf, ln2_g + l * kHA,
                                                 ln2_b + l * kHA, att_bf);
  }
  de_loss_kernel<<<64, 256, 0, stream>>>(att_bf, de_wt, de_b, pred_u, out);
}

// Round 9
// 413.293 us; speedup vs baseline: 1.2007x; 1.0556x over previous
//
#include <hip/hip_runtime.h>

// Problem constants (AttentionalCopula)
constexpr int kB = 16, kD = 256, kNH = 512, kNV = 256, kW = 768;
constexpr int kL = 4, kH = 8, kA = 64, kHA = 512, kM = 512, kR = 128;
constexpr int kKP = 288;  // K=257 zero-padded to multiple of 32
constexpr int kRows = kB * kNV;  // 4096

typedef __bf16 bf16x8 __attribute__((ext_vector_type(8)));
typedef __bf16 bf16x4 __attribute__((ext_vector_type(4)));
typedef float f32x4 __attribute__((ext_vector_type(4)));

__device__ inline void load_lds16(const __bf16* g, __bf16* l) {
  __builtin_amdgcn_global_load_lds(
      (const __attribute__((address_space(1))) void*)g,
      (__attribute__((address_space(3))) void*)l, 16, 0, 0);
}

// ---------------- merged prep kernel (1 launch, block-range sections) --------
// A: ki fill (coalesced both sides)           [0, 13824)
// B: kv weights transpose (LDS-tiled)         [13824, 14400)
// C: ff weights transpose (LDS-tiled)         [14400, 17472)
// D: ds_w transpose                           [17472, 17600)
// E: de_w transpose                           [17600, 17664)
// F: kvb gather + out zero                    [17664, 17681)
constexpr int kP1 = kB * kW * kKP;  // 3,538,944 -> 13824 blocks
constexpr int kPrepBlocks = 17681;

__global__ void prep_kernel(const float* __restrict__ hist,
                            const float* __restrict__ hist_u,
                            const float* __restrict__ pred,
                            const float* __restrict__ pred_u,
                            const float* __restrict__ kw,
                            const float* __restrict__ vw,
                            const float* __restrict__ w1,
                            const float* __restrict__ w2,
                            const float* __restrict__ w3,
                            const float* __restrict__ ds_w,
                            const float* __restrict__ de_w,
                            const float* __restrict__ key_b,
                            const float* __restrict__ val_b,
                            __bf16* __restrict__ ki,
                            __bf16* __restrict__ kvwt,
                            __bf16* __restrict__ ffwt,
                            __bf16* __restrict__ ds_wt,
                            __bf16* __restrict__ de_wt,
                            float* __restrict__ kvb,
                            float* __restrict__ outz) {
  __shared__ float ld[2080];  // 32x65 (B) / 32x33 (C,D,E)
  const int bid = blockIdx.x;
  const int t = threadIdx.x;
  if (bid < 13824) {
    // ---- A: ki fill ----
    int i = bid * 256 + t;
    int d = i % kKP;
    int bw = i / kKP;
    int w = bw % kW;
    int b = bw / kW;
    float v = 0.f;
    if (d < 257) {
      if (w < kNH)
        v = (d < kD) ? hist[((size_t)b * kNH + w) * kD + d] : hist_u[b * kNH + w];
      else {
        int p = w - kNH;
        v = (d < kD) ? pred[((size_t)b * kNV + p) * kD + d] : pred_u[b * kNV + p];
      }
    }
    ki[i] = (__bf16)v;
  } else if (bid < 14400) {
    // ---- B: kv weight transpose: kvwt[c][d] = w[l,h,d,a=c&63] ----
    int bb = bid - 13824;            // 0..575
    bool isv = bb >= 288;
    int rem = isv ? bb - 288 : bb;   // 0..287
    int pair = rem / 9;              // (l,h) 0..31
    int dt = rem - pair * 9;         // 0..8
    int d0 = dt * 32;
    const float* src = (isv ? vw : kw) + (size_t)pair * 257 * 64;
    int a = t & 63, dg = t >> 6;
#pragma unroll
    for (int ii = 0; ii < 8; ++ii) {
      int d = d0 + dg * 8 + ii;
      ld[(dg * 8 + ii) * 65 + a] = (d < 257) ? src[(size_t)d * 64 + a] : 0.f;
    }
    __syncthreads();
    int r = t >> 2, seg = t & 3;
    bf16x8 v;
#pragma unroll
    for (int j = 0; j < 8; ++j) v[j] = (__bf16)ld[(seg * 8 + j) * 65 + r];
    *(bf16x8*)&kvwt[((size_t)(isv ? 2048 : 0) + pair * 64 + r) * 288 + d0 +
                    seg * 8] = v;
  } else if (bid < 17472) {
    // ---- C: ff weight transpose: ffwt[mat][n][k] = src[k][n] ----
    int cc = bid - 14400;  // 0..3071
    int mat = cc >> 8;
    int tile = cc & 255;
    int n0 = (tile & 15) * 32, k0 = (tile >> 4) * 32;
    int l = mat / 3, which = mat - l * 3;
    const float* src = (which == 0 ? w1 : which == 1 ? w2 : w3) +
                       (size_t)l * 262144;
    int col = t & 31, kr = t >> 5;
#pragma unroll
    for (int p = 0; p < 4; ++p)
      ld[(kr + p * 8) * 33 + col] = src[(size_t)(k0 + kr + p * 8) * 512 + n0 + col];
    __syncthreads();
    int nr = t >> 3, seg = t & 7;
    bf16x4 v;
#pragma unroll
    for (int j = 0; j < 4; ++j) v[j] = (__bf16)ld[(seg * 4 + j) * 33 + nr];
    *(bf16x4*)&ffwt[(size_t)mat * 262144 + (n0 + nr) * 512 + k0 + seg * 4] = v;
  } else if (bid < 17600) {
    // ---- D: ds_w transpose: ds_wt[n][k] = ds_w[k][n] (256k x 512n) ----
    int cc = bid - 17472;  // 0..127
    int n0 = (cc & 15) * 32, k0 = (cc >> 4) * 32;
    int col = t & 31, kr = t >> 5;
#pragma unroll
    for (int p = 0; p < 4; ++p)
      ld[(kr + p * 8) * 33 + col] = ds_w[(size_t)(k0 + kr + p * 8) * 512 + n0 + col];
    __syncthreads();
    int nr = t >> 3, seg = t & 7;
    bf16x4 v;
#pragma unroll
    for (int j = 0; j < 4; ++j) v[j] = (__bf16)ld[(seg * 4 + j) * 33 + nr];
    *(bf16x4*)&ds_wt[(n0 + nr) * 256 + k0 + seg * 4] = v;
  } else if (bid < 17664) {
    // ---- E: de_w transpose: de_wt[n][k] = de_w[k][n] (512k x 128n) ----
    int cc = bid - 17600;  // 0..63
    int n0 = (cc & 3) * 32, k0 = (cc >> 2) * 32;
    int col = t & 31, kr = t >> 5;
#pragma unroll
    for (int p = 0; p < 4; ++p)
      ld[(kr + p * 8) * 33 + col] = de_w[(size_t)(k0 + kr + p * 8) * 128 + n0 + col];
    __syncthreads();
    int nr = t >> 3, seg = t & 7;
    bf16x4 v;
#pragma unroll
    for (int j = 0; j < 4; ++j) v[j] = (__bf16)ld[(seg * 4 + j) * 33 + nr];
    *(bf16x4*)&de_wt[(n0 + nr) * 512 + k0 + seg * 4] = v;
  } else {
    // ---- F: kvb + out zero ----
    int j = (bid - 17664) * 256 + t;
    if (j < 4096) {
      bool isv = j >= 2048;
      int cc = isv ? j - 2048 : j;
      int l = cc >> 9, rest = cc & 511;
      kvb[j] = isv ? val_b[l * 512 + rest] : key_b[l * 512 + rest];
    } else if (j < 4112) {
      outz[j - 4096] = 0.f;
    }
  }
}

// ---- generic bf16 MFMA GEMM core (DEPTH-buffer counted-vmcnt pipeline) ------
// T4 pattern: distance-(DEPTH-1) prefetch, raw s_barrier + counted s_waitcnt
// so prefetch global_load_lds stay in flight across barriers (never drain
// vmcnt to 0 mid-loop). DEPTH=3 for gemm3, DEPTH=4 for ff.
template <int BN, int OMODE, bool RELU, bool KIMAP, bool BIASROW, int DEPTH>
__device__ __forceinline__ void gemm_core(
    int bxv, int byv, const __bf16* __restrict__ A,
    const __bf16* __restrict__ Bt, const float* __restrict__ bias,
    void* __restrict__ Cout, __bf16* __restrict__ Cout2, int K, int lda,
    int ldc, __bf16* Sm) {
  constexpr int JN = BN / 32;
  constexpr int BROWS = BN / 4;
  constexpr int SSTEP = (128 + BN) * 32;       // one stage buffer, bf16 elems
  constexpr int LPS = (BN == 128) ? 4 : 3;     // global_load_lds per wave/stage
  constexpr int AH = DEPTH - 1;                // stages prefetched ahead
  const int t = threadIdx.x;
  const int wid = t >> 6;
  const int lane = t & 63;
  const int bm = byv * 128;
  const int bn = bxv * BN;
  const int wm = (wid >> 1) * 64;
  const int wn = (wid & 1) * (BN / 2);
  const int sr = lane >> 2, sc = lane & 3;
  const int skey = (sr >> 1) & 3;
  const int abase = KIMAP ? ((bm >> 8) * 768 + 512 + (bm & 255)) : bm;
  const __bf16* Ag = A + (size_t)(abase + wid * 32 + sr) * lda + (sc ^ skey) * 8;
  const __bf16* Bg = Bt + (size_t)(bn + wid * BROWS + sr) * K + (sc ^ skey) * 8;

  auto stage = [&](int k0, __bf16* buf) {
    __bf16* As = buf;
    __bf16* Bs = buf + 4096;
    load_lds16(Ag + k0, As + (wid * 32) * 32);
    load_lds16(Ag + (size_t)16 * lda + k0, As + (wid * 32 + 16) * 32);
    load_lds16(Bg + k0, Bs + (wid * BROWS) * 32);
    if (BN == 128)
      load_lds16(Bg + (size_t)16 * K + k0, Bs + (wid * BROWS + 16) * 32);
  };

  f32x4 acc[4][JN] = {};
  const int q = lane >> 4, mr = lane & 15;
  const int rkey = (mr >> 1) & 3;
  const int nst = K >> 5;
  __bf16* b0 = Sm;
  __bf16* b1 = Sm + SSTEP;
  __bf16* b2 = Sm + 2 * SSTEP;
  __bf16* b3 = (DEPTH == 4) ? Sm + 3 * SSTEP : nullptr;
  stage(0, b0);
  stage(32, b1);
  if constexpr (DEPTH == 4) stage(64, b2);
  asm volatile("s_waitcnt vmcnt(%0)" ::"n"((AH - 1) * LPS) : "memory");
  __builtin_amdgcn_s_barrier();
  for (int k = 0; k < nst; ++k) {
    if (k + AH < nst) {
      if constexpr (DEPTH == 4) stage((k + AH) << 5, b3);
      else stage((k + AH) << 5, b2);
    }
    bf16x8 af[4], bfr[JN];
#pragma unroll
    for (int i = 0; i < 4; ++i)
      af[i] = *(const bf16x8*)(b0 + (wm + i * 16 + mr) * 32 + (q ^ rkey) * 8);
#pragma unroll
    for (int j = 0; j < JN; ++j)
      bfr[j] =
          *(const bf16x8*)(b0 + 4096 + (wn + j * 16 + mr) * 32 + (q ^ rkey) * 8);
#pragma unroll
    for (int i = 0; i < 4; ++i)
#pragma unroll
      for (int j = 0; j < JN; ++j)
        acc[i][j] = __builtin_amdgcn_mfma_f32_16x16x32_bf16(af[i], bfr[j],
                                                            acc[i][j], 0, 0, 0);
    if (k + AH + 1 <= nst)
      asm volatile("s_waitcnt vmcnt(%0)" ::"n"((AH - 1) * LPS) : "memory");
    else if (DEPTH == 4 && k + AH == nst + 1)
      asm volatile("s_waitcnt vmcnt(%0)" ::"n"(LPS) : "memory");
    else
      asm volatile("s_waitcnt vmcnt(0)" ::: "memory");
    __builtin_amdgcn_s_barrier();
    if constexpr (DEPTH == 4) {
      __bf16* tp = b0; b0 = b1; b1 = b2; b2 = b3; b3 = tp;
    } else {
      __bf16* tp = b0; b0 = b1; b1 = b2; b2 = tp;
    }
  }
  // ---- epilogue: stage C in LDS, coalesced write-out ----
  if (OMODE == 1) {
    constexpr int PS = BN + 8;
    __bf16* Cs = Sm;
#pragma unroll
    for (int j = 0; j < JN; ++j) {
      float bscol = BIASROW ? 0.f : bias[bn + wn + j * 16 + mr];
#pragma unroll
      for (int i = 0; i < 4; ++i) {
#pragma unroll
        for (int r = 0; r < 4; ++r) {
          float v = acc[i][j][r] +
                    (BIASROW ? bias[bm + wm + i * 16 + q * 4 + r] : bscol);
          if (RELU) v = fmaxf(v, 0.f);
          Cs[(wm + i * 16 + q * 4 + r) * PS + wn + j * 16 + mr] = (__bf16)v;
        }
      }
    }
    __syncthreads();
    constexpr int lpr = BN / 8;
    constexpr int rpi = 512 / BN;
    const int rl = lane / lpr, cl = (lane % lpr) * 8;
#pragma unroll
    for (int it = 0; it < BN / 16; ++it) {
      int row = wid * 32 + it * rpi + rl;
      bf16x8 v = *(const bf16x8*)&Cs[row * PS + cl];
      *(bf16x8*)((__bf16*)Cout + (size_t)(bm + row) * ldc + bn + cl) = v;
    }
  } else {
    constexpr int PSF = BN + 4;
    float* Csf = (float*)Sm;
#pragma unroll
    for (int j = 0; j < JN; ++j) {
      float bscol = bias[bn + wn + j * 16 + mr];
#pragma unroll
      for (int i = 0; i < 4; ++i) {
#pragma unroll
        for (int r = 0; r < 4; ++r) {
          float v = acc[i][j][r] + bscol;
          if (RELU) v = fmaxf(v, 0.f);
          Csf[(wm + i * 16 + q * 4 + r) * PSF + wn + j * 16 + mr] = v;
        }
      }
    }
    __syncthreads();
    const int rl = lane >> 4, cl = (lane & 15) * 4;
#pragma unroll
    for (int it = 0; it < 8; ++it) {
      int row = wid * 32 + it * 4 + rl;
      f32x4 v = *(const f32x4*)&Csf[row * PSF + cl];
      size_t gidx = (size_t)(bm + row) * ldc + bn + cl;
      *(f32x4*)((float*)Cout + gidx) = v;
      bf16x4 vb = {(__bf16)v[0], (__bf16)v[1], (__bf16)v[2], (__bf16)v[3]};
      *(bf16x4*)(Cout2 + gidx) = vb;
    }
  }
}

// ---------------- fused ds + keys + vT GEMM (one launch, 3328 blocks) ----------------
__global__ __launch_bounds__(256) void gemm3_kernel(
    const __bf16* __restrict__ ki, const __bf16* __restrict__ ds_wt,
    const float* __restrict__ ds_b, float* __restrict__ att,
    __bf16* __restrict__ att_bf, const __bf16* __restrict__ kv_wt,
    const float* __restrict__ kvb, __bf16* __restrict__ kvs_k,
    __bf16* __restrict__ vT) {
  __shared__ __bf16 smem[24576];
  int bid = blockIdx.x;  // identity mapping (both swizzles measured worse)
  if (bid < 256) {
    gemm_core<64, 2, false, true, false, 3>(bid & 7, bid >> 3, ki, ds_wt, ds_b,
                                            att, att_bf, 256, kKP, 512, smem);
  } else if (bid < 1792) {
    int b2 = bid - 256;
    gemm_core<128, 1, false, false, false, 3>(b2 & 15, b2 >> 4, ki, kv_wt, kvb,
                                              kvs_k, nullptr, kKP, kKP, 2048,
                                              smem);
  } else {
    int b3 = bid - 1792;
    gemm_core<128, 1, false, false, true, 3>(b3 % 96, b3 / 96,
                                             kv_wt + (size_t)2048 * kKP, ki,
                                             kvb + 2048, vT, nullptr, kKP, kKP,
                                             12288, smem);
  }
}

// ---------------- ff GEMMs (gemm_core wrappers, 4-deep pipeline) ------------
template <bool RELU>
__global__ __launch_bounds__(256) void gemm_ff_kernel(
    const __bf16* __restrict__ A, const __bf16* __restrict__ Bt,
    const float* __restrict__ bias, __bf16* __restrict__ Cout) {
  __shared__ __bf16 smem[24576];
  gemm_core<64, 1, RELU, false, false, 4>(blockIdx.x, blockIdx.y, A, Bt, bias,
                                          Cout, nullptr, 512, 512, 512, smem);
}

// ---------------- MFMA flash attention (S^T variant, reg-prefetched) --------
__global__ __launch_bounds__(256) void attn_mfma_kernel(
    const __bf16* __restrict__ attbf, const __bf16* __restrict__ kvs_k,
    const __bf16* __restrict__ vT, __bf16* __restrict__ outbf, int l) {
  const int id = blockIdx.x;
  const int kk = id >> 3;
  const int b = ((kk >> 5) << 3) | (id & 7);
  const int qt = kk & 3;
  const int h = (kk >> 2) & 7;
  __shared__ __bf16 Ks[64 * 72];
  __shared__ __bf16 Vt[64 * 72];
  __shared__ __bf16 Ps[64 * 72];
  const int t = threadIdx.x;
  const int w = t >> 6, lane = t & 63;
  const int quad = lane >> 4, mr = lane & 15;
  bf16x8 aq[2];
  {
    const __bf16* qp = attbf + ((size_t)(b * kNV + qt * 64 + w * 16 + mr) * kHA +
                                h * kA + quad * 8);
    aq[0] = *(const bf16x8*)qp;
    aq[1] = *(const bf16x8*)(qp + 32);
  }
  f32x4 o[4] = {};
  float m_ = -1e30f, l_ = 0.f;
  const int cmax = kNH + qt * 64;
  const int pr = t >> 2, pc = t & 3;
  const __bf16* kbase = kvs_k + ((size_t)(b * kW + pr) * 2048 + l * 512 + h * kA);
  const __bf16* vbase = vT + (size_t)(l * 512 + h * kA + pr) * 12288 + b * kW;
  bf16x8 kc0, kc1, vc0, vc1;
  kc0 = *(const bf16x8*)(kbase + pc * 8);
  kc1 = *(const bf16x8*)(kbase + pc * 8 + 32);
  vc0 = *(const bf16x8*)(vbase + pc * 16);
  vc1 = *(const bf16x8*)(vbase + pc * 16 + 8);
  for (int c0 = 0; c0 <= cmax; c0 += 64) {
    __syncthreads();
    *(bf16x8*)&Ks[pr * 72 + pc * 8] = kc0;
    *(bf16x8*)&Ks[pr * 72 + pc * 8 + 32] = kc1;
    *(bf16x8*)&Vt[pr * 72 + pc * 16] = vc0;
    *(bf16x8*)&Vt[pr * 72 + pc * 16 + 8] = vc1;
    __syncthreads();
    if (c0 + 64 <= cmax) {
      const __bf16* kp = kbase + (size_t)(c0 + 64) * 2048;
      const __bf16* vp = vbase + c0 + 64;
      kc0 = *(const bf16x8*)(kp + pc * 8);
      kc1 = *(const bf16x8*)(kp + pc * 8 + 32);
      vc0 = *(const bf16x8*)(vp + pc * 16);
      vc1 = *(const bf16x8*)(vp + pc * 16 + 8);
    }
    // ---- S^T = K·Q^T ----
    f32x4 s[4];
#pragma unroll
    for (int j = 0; j < 4; ++j) {
      bf16x8 ak0 = *(const bf16x8*)&Ks[(j * 16 + mr) * 72 + quad * 8];
      bf16x8 ak1 = *(const bf16x8*)&Ks[(j * 16 + mr) * 72 + quad * 8 + 32];
      f32x4 z = {};
      z = __builtin_amdgcn_mfma_f32_16x16x32_bf16(ak0, aq[0], z, 0, 0, 0);
      z = __builtin_amdgcn_mfma_f32_16x16x32_bf16(ak1, aq[1], z, 0, 0, 0);
      s[j] = z;
    }
    const int lim = cmax - c0;
    float sv[16], mx = -1e30f;
#pragma unroll
    for (int j = 0; j < 4; ++j)
#pragma unroll
      for (int r = 0; r < 4; ++r) {
        int p = j * 16 + quad * 4 + r;
        float x = (p < lim + mr) ? s[j][r] * 0.125f : -1e30f;
        sv[j * 4 + r] = x;
        mx = fmaxf(mx, x);
      }
    mx = fmaxf(mx, __shfl_xor(mx, 16));
    mx = fmaxf(mx, __shfl_xor(mx, 32));
    float mnew = fmaxf(m_, mx);
    float corr = __expf(m_ - mnew);
    float rs = 0.f;
#pragma unroll
    for (int i = 0; i < 16; ++i) {
      sv[i] = __expf(sv[i] - mnew);
      rs += sv[i];
    }
    rs += __shfl_xor(rs, 16);
    rs += __shfl_xor(rs, 32);
    l_ = l_ * corr + rs;
    m_ = mnew;
#pragma unroll
    for (int j = 0; j < 4; ++j) {
      bf16x4 pk = {(__bf16)sv[j * 4 + 0], (__bf16)sv[j * 4 + 1],
                   (__bf16)sv[j * 4 + 2], (__bf16)sv[j * 4 + 3]};
      *(bf16x4*)&Ps[(w * 16 + mr) * 72 + j * 16 + quad * 4] = pk;
    }
#pragma unroll
    for (int r = 0; r < 4; ++r) {
      float cr = __shfl(corr, quad * 4 + r);
#pragma unroll
      for (int j = 0; j < 4; ++j) o[j][r] *= cr;
    }
    bf16x8 ap0 = *(const bf16x8*)&Ps[(w * 16 + mr) * 72 + quad * 8];
    bf16x8 ap1 = *(const bf16x8*)&Ps[(w * 16 + mr) * 72 + quad * 8 + 32];
#pragma unroll
    for (int j = 0; j < 4; ++j) {
      bf16x8 b0 = *(const bf16x8*)&Vt[(j * 16 + mr) * 72 + quad * 8];
      bf16x8 b1 = *(const bf16x8*)&Vt[(j * 16 + mr) * 72 + quad * 8 + 32];
      o[j] = __builtin_amdgcn_mfma_f32_16x16x32_bf16(ap0, b0, o[j], 0, 0, 0);
      o[j] = __builtin_amdgcn_mfma_f32_16x16x32_bf16(ap1, b1, o[j], 0, 0, 0);
    }
  }
  float invl = 1.f / l_;
#pragma unroll
  for (int r = 0; r < 4; ++r) {
    float ir = __shfl(invl, quad * 4 + r);
    int row = b * kNV + qt * 64 + w * 16 + quad * 4 + r;
#pragma unroll
    for (int j = 0; j < 4; ++j)
      outbf[(size_t)row * kHA + h * kA + j * 16 + mr] = (__bf16)(o[j][r] * ir);
  }
}

// --------- att = LN(att + add_bf); wave-per-row, no LDS, no barrier ---------
__global__ __launch_bounds__(256) void add_ln_kernel(
    float* __restrict__ att, const __bf16* __restrict__ addbf,
    const float* __restrict__ g, const float* __restrict__ be,
    __bf16* __restrict__ attbf) {
  const int w = threadIdx.x >> 6, lane = threadIdx.x & 63;
  const int row = blockIdx.x * 4 + w;
  const int c0 = lane * 8;
  const size_t base = (size_t)row * kHA + c0;
  float4 a0 = *(const float4*)(att + base);
  float4 a1 = *(const float4*)(att + base + 4);
  bf16x8 dv = *(const bf16x8*)(addbf + base);
  float x[8] = {a0.x + (float)dv[0], a0.y + (float)dv[1], a0.z + (float)dv[2],
                a0.w + (float)dv[3], a1.x + (float)dv[4], a1.y + (float)dv[5],
                a1.z + (float)dv[6], a1.w + (float)dv[7]};
  float s = 0.f, q = 0.f;
#pragma unroll
  for (int j = 0; j < 8; ++j) { s += x[j]; q += x[j] * x[j]; }
#pragma unroll
  for (int o = 1; o < 64; o <<= 1) {
    s += __shfl_xor(s, o);
    q += __shfl_xor(q, o);
  }
  const float mean = s * (1.f / kHA);
  const float inv = rsqrtf(q * (1.f / kHA) - mean * mean + 1e-5f);
  float4 g0 = *(const float4*)(g + c0);
  float4 g1 = *(const float4*)(g + c0 + 4);
  float4 e0 = *(const float4*)(be + c0);
  float4 e1 = *(const float4*)(be + c0 + 4);
  float y[8];
  y[0] = g0.x * (x[0] - mean) * inv + e0.x;
  y[1] = g0.y * (x[1] - mean) * inv + e0.y;
  y[2] = g0.z * (x[2] - mean) * inv + e0.z;
  y[3] = g0.w * (x[3] - mean) * inv + e0.w;
  y[4] = g1.x * (x[4] - mean) * inv + e1.x;
  y[5] = g1.y * (x[5] - mean) * inv + e1.y;
  y[6] = g1.z * (x[6] - mean) * inv + e1.z;
  y[7] = g1.w * (x[7] - mean) * inv + e1.w;
  *(float4*)(att + base) = (float4){y[0], y[1], y[2], y[3]};
  *(float4*)(att + base + 4) = (float4){y[4], y[5], y[6], y[7]};
  bf16x8 yb = {(__bf16)y[0], (__bf16)y[1], (__bf16)y[2], (__bf16)y[3],
               (__bf16)y[4], (__bf16)y[5], (__bf16)y[6], (__bf16)y[7]};
  *(bf16x8*)(attbf + base) = yb;
}

// ------- fused LN2(l=3) + de-projection + loss (atomic into out) ------------
// Block owns 64 complete rows: phase A computes LN2(att + ff3) into a
// row-XOR-swizzled LDS A-tile; MFMA K-loop reads A from LDS.
__global__ __launch_bounds__(256) void de_loss_kernel(
    const float* __restrict__ att, const __bf16* __restrict__ fbf,
    const float* __restrict__ g2, const float* __restrict__ b2,
    const __bf16* __restrict__ de_wt, const float* __restrict__ de_b,
    const float* __restrict__ pred_u, float* __restrict__ out) {
  __shared__ __bf16 Als[64 * 512];  // 64 KB, row-XOR swizzled
  __shared__ float red[4];
  const int blk = blockIdx.x;
  const int t = threadIdx.x;
  const int w = t >> 6, lane = t & 63, quad = lane >> 4, mr = lane & 15;
  // ---- phase A: LN2 into LDS ----
  {
    const int c0 = lane * 8;
    float4 ga = *(const float4*)(g2 + c0);
    float4 gb = *(const float4*)(g2 + c0 + 4);
    float4 ba = *(const float4*)(b2 + c0);
    float4 bb = *(const float4*)(b2 + c0 + 4);
    for (int rr = 0; rr < 16; ++rr) {
      const int lrow = w * 16 + rr;
      const size_t base = (size_t)(blk * 64 + lrow) * 512 + c0;
      float4 a0 = *(const float4*)(att + base);
      float4 a1 = *(const float4*)(att + base + 4);
      bf16x8 dv = *(const bf16x8*)(fbf + base);
      float x[8] = {a0.x + (float)dv[0], a0.y + (float)dv[1],
                    a0.z + (float)dv[2], a0.w + (float)dv[3],
                    a1.x + (float)dv[4], a1.y + (float)dv[5],
                    a1.z + (float)dv[6], a1.w + (float)dv[7]};
      float s = 0.f, q = 0.f;
#pragma unroll
      for (int j = 0; j < 8; ++j) { s += x[j]; q += x[j] * x[j]; }
#pragma unroll
      for (int o = 1; o < 64; o <<= 1) {
        s += __shfl_xor(s, o);
        q += __shfl_xor(q, o);
      }
      const float mean = s * (1.f / kHA);
      const float inv = rsqrtf(q * (1.f / kHA) - mean * mean + 1e-5f);
      bf16x8 yv = {(__bf16)(ga.x * (x[0] - mean) * inv + ba.x),
                   (__bf16)(ga.y * (x[1] - mean) * inv + ba.y),
                   (__bf16)(ga.z * (x[2] - mean) * inv + ba.z),
                   (__bf16)(ga.w * (x[3] - mean) * inv + ba.w),
                   (__bf16)(gb.x * (x[4] - mean) * inv + bb.x),
                   (__bf16)(gb.y * (x[5] - mean) * inv + bb.y),
                   (__bf16)(gb.z * (x[6] - mean) * inv + bb.z),
                   (__bf16)(gb.w * (x[7] - mean) * inv + bb.w)};
      *(bf16x8*)&Als[lrow * 512 + ((lane ^ (lrow & 7)) << 3)] = yv;
    }
  }
  __syncthreads();
  // ---- MFMA K-loop (A from LDS) ----
  const int row0 = blk * 64 + w * 16;
  const int lrowA = w * 16 + mr;
  f32x4 acc[8] = {};
#pragma unroll 4
  for (int k0 = 0; k0 < 512; k0 += 32) {
    const int grp = (((k0 >> 3) + quad) ^ (lrowA & 7)) << 3;
    bf16x8 a = *(const bf16x8*)&Als[lrowA * 512 + grp];
#pragma unroll
    for (int j = 0; j < 8; ++j) {
      bf16x8 bb =
          *(const bf16x8*)(de_wt + (size_t)(j * 16 + mr) * 512 + k0 + quad * 8);
      acc[j] = __builtin_amdgcn_mfma_f32_16x16x32_bf16(a, bb, acc[j], 0, 0, 0);
    }
  }
  float dbv[8];
#pragma unroll
  for (int j = 0; j < 8; ++j) dbv[j] = de_b[j * 16 + mr];
  float lpacc = 0.f;
#pragma unroll
  for (int r = 0; r < 4; ++r) {
    int row = row0 + quad * 4 + r;
    int v = row & 255;
    float lg[8], mx = -1e30f;
#pragma unroll
    for (int j = 0; j < 8; ++j) {
      lg[j] = acc[j][r] + dbv[j];
      mx = fmaxf(mx, lg[j]);
    }
    mx = fmaxf(mx, __shfl_xor(mx, 1));
    mx = fmaxf(mx, __shfl_xor(mx, 2));
    mx = fmaxf(mx, __shfl_xor(mx, 4));
    mx = fmaxf(mx, __shfl_xor(mx, 8));
    float se = 0.f;
#pragma unroll
    for (int j = 0; j < 8; ++j) se += __expf(lg[j] - mx);
    se += __shfl_xor(se, 1);
    se += __shfl_xor(se, 2);
    se += __shfl_xor(se, 4);
    se += __shfl_xor(se, 8);
    float lse = mx + __logf(se);
    float u = pred_u[(row >> 8) * 256 + v];
    int tgt = (int)floorf(u * 128.f);
    tgt = max(0, min(127, tgt));
    float cand = (mr == (tgt & 15)) ? lg[tgt >> 4] : 0.f;
    cand += __shfl_xor(cand, 1);
    cand += __shfl_xor(cand, 2);
    cand += __shfl_xor(cand, 4);
    cand += __shfl_xor(cand, 8);
    float lp = (v >= 1) ? (4.8520302639196171f + cand - lse) : 0.f;  // ln(128)
    lpacc += lp;
  }
  lpacc += __shfl_xor(lpacc, 16);
  lpacc += __shfl_xor(lpacc, 32);
  if (lane == 0) red[w] = lpacc;
  __syncthreads();
  if (t == 0)
    atomicAdd(&out[blk >> 2], -(red[0] + red[1] + red[2] + red[3]));
}

extern "C" void kernel_launch(void* const* d_in, const int* in_sizes, int n_in,
                              void* d_out, int out_size, void* d_ws, size_t ws_size,
                              hipStream_t stream) {
  const float* hist   = (const float*)d_in[0];
  const float* hist_u = (const float*)d_in[1];
  const float* pred   = (const float*)d_in[2];
  const float* pred_u = (const float*)d_in[3];
  const float* ds_w   = (const float*)d_in[4];
  const float* ds_b   = (const float*)d_in[5];
  const float* key_w  = (const float*)d_in[6];
  const float* key_b  = (const float*)d_in[7];
  const float* val_w  = (const float*)d_in[8];
  const float* val_b  = (const float*)d_in[9];
  const float* ln1_g  = (const float*)d_in[10];
  const float* ln1_b  = (const float*)d_in[11];
  const float* ln2_g  = (const float*)d_in[12];
  const float* ln2_b  = (const float*)d_in[13];
  const float* ff_w1  = (const float*)d_in[14];
  const float* ff_b1  = (const float*)d_in[15];
  const float* ff_w2  = (const float*)d_in[16];
  const float* ff_b2  = (const float*)d_in[17];
  const float* ff_w3  = (const float*)d_in[18];
  const float* ff_b3  = (const float*)d_in[19];
  const float* de_w   = (const float*)d_in[20];
  const float* de_b   = (const float*)d_in[21];
  float* out = (float*)d_out;

  char* ws = (char*)d_ws;
  size_t off = 0;
  auto alloc = [&](size_t bytes) { char* p = ws + off; off += bytes; return p; };
  __bf16* ki_bf  = (__bf16*)alloc((size_t)kB * kW * kKP * 2);       // 7.1 MB
  __bf16* kv_wt  = (__bf16*)alloc((size_t)4096 * kKP * 2);          // 2.4 MB
  __bf16* ffw_t  = (__bf16*)alloc((size_t)12 * 512 * 512 * 2);      // 6.3 MB
  __bf16* ds_wt  = (__bf16*)alloc((size_t)512 * 256 * 2);
  __bf16* de_wt  = (__bf16*)alloc((size_t)128 * 512 * 2);
  float*  kvb    = (float*)alloc((size_t)4096 * 4);
  __bf16* kvs_k  = (__bf16*)alloc((size_t)kB * kW * 2048 * 2);      // 50.3 MB
  __bf16* vT     = (__bf16*)alloc((size_t)2048 * 12288 * 2);        // 50.3 MB
  float*  att    = (float*)alloc((size_t)kRows * kHA * 4);          // 8.4 MB
  __bf16* att_bf = (__bf16*)alloc((size_t)kRows * kHA * 2);
  __bf16* tmp_bf = (__bf16*)alloc((size_t)kRows * kHA * 2);
  __bf16* ff1_bf = (__bf16*)alloc((size_t)kRows * kM * 2);
  __bf16* ff2_bf = (__bf16*)alloc((size_t)kRows * kM * 2);

  prep_kernel<<<kPrepBlocks, 256, 0, stream>>>(
      hist, hist_u, pred, pred_u, key_w, val_w, ff_w1, ff_w2, ff_w3, ds_w, de_w,
      key_b, val_b, ki_bf, kv_wt, ffw_t, ds_wt, de_wt, kvb, out);

  // ds + keys + vT in one launch
  gemm3_kernel<<<3328, 256, 0, stream>>>(ki_bf, ds_wt, ds_b, att, att_bf, kv_wt,
                                         kvb, kvs_k, vT);

  for (int l = 0; l < kL; ++l) {
    attn_mfma_kernel<<<512, 256, 0, stream>>>(att_bf, kvs_k, vT, tmp_bf, l);
    add_ln_kernel<<<kRows / 4, 256, 0, stream>>>(att, tmp_bf, ln1_g + l * kHA,
                                                 ln1_b + l * kHA, att_bf);
    gemm_ff_kernel<true><<<dim3(kM / 64, kRows / 128), 256, 0, stream>>>(
        att_bf, ffw_t + (size_t)(l * 3) * 262144, ff_b1 + l * kM, ff1_bf);
    gemm_ff_kernel<true><<<dim3(kM / 64, kRows / 128), 256, 0, stream>>>(
        ff1_bf, ffw_t + (size_t)(l * 3 + 1) * 262144, ff_b2 + l * kM, ff2_bf);
    gemm_ff_kernel<false><<<dim3(kHA / 64, kRows / 128), 256, 0, stream>>>(
        ff2_bf, ffw_t + (size_t)(l * 3 + 2) * 262144, ff_b3 + l * kHA, tmp_bf);
    if (l < kL - 1)
      add_ln_kernel<<<kRows / 4, 256, 0, stream>>>(att, tmp_bf,
                                                   ln2_g + l * kHA,
                                                   ln2_b + l * kHA, att_bf);
  }
  // final LN2 fused into de_loss (att holds LN1-out y of layer 3; tmp_bf = ff3)
  de_loss_kernel<<<64, 256, 0, stream>>>(att, tmp_bf, ln2_g + 3 * kHA,
                                         ln2_b + 3 * kHA, de_wt, de_b, pred_u,
                                         out);
}